// Round 2
// baseline (1464.189 us; speedup 1.0000x reference)
//
#include <hip/hip_runtime.h>
#include <hip/hip_bf16.h>

// Problem constants (verified against in_sizes at launch)
#define HEADS 8
#define CH    64
#define HC    512   // HEADS*CH
#define NGR   64
#define NEGS  0.2f

__device__ __forceinline__ float lrelu(float v) {
    return (v > 0.f) ? v : NEGS * v;
}

// ---------------------------------------------------------------------------
// BN stats: per-feature sum / sumsq over N rows (16 features)
__global__ void bn_stats_kernel(const float* __restrict__ x, float* __restrict__ stats, int N) {
    int t0 = blockIdx.x * blockDim.x + threadIdx.x;
    int stride = gridDim.x * blockDim.x;
    float s[16], q[16];
#pragma unroll
    for (int i = 0; i < 16; i++) { s[i] = 0.f; q[i] = 0.f; }
    for (int r = t0; r < N; r += stride) {
        const float4* xr = (const float4*)(x + (size_t)r * 16);
#pragma unroll
        for (int i = 0; i < 4; i++) {
            float4 v = xr[i];
            s[4*i+0] += v.x; q[4*i+0] += v.x * v.x;
            s[4*i+1] += v.y; q[4*i+1] += v.y * v.y;
            s[4*i+2] += v.z; q[4*i+2] += v.z * v.z;
            s[4*i+3] += v.w; q[4*i+3] += v.w * v.w;
        }
    }
#pragma unroll
    for (int k = 0; k < 16; k++) {
        float vs = s[k], vq = q[k];
        for (int off = 32; off; off >>= 1) {
            vs += __shfl_down(vs, off);
            vq += __shfl_down(vq, off);
        }
        if ((threadIdx.x & 63) == 0) {
            atomicAdd(stats + k, vs);
            atomicAdd(stats + 16 + k, vq);
        }
    }
}

// stats[32..47] = scale, stats[48..63] = shift
__global__ void bn_finalize_kernel(float* __restrict__ stats,
                                   const float* __restrict__ gamma,
                                   const float* __restrict__ beta, int N) {
    int t = threadIdx.x;
    if (t < 16) {
        float invn = 1.f / (float)N;
        float mean = stats[t] * invn;
        float var  = stats[16 + t] * invn - mean * mean;
        float sc   = gamma[t] * rsqrtf(var + 1e-5f);
        stats[32 + t] = sc;
        stats[48 + t] = beta[t] - mean * sc;
    }
}

// ---------------------------------------------------------------------------
// CSR build over dst (edges + self loops). E2 = E + N.
__global__ void count_kernel(const int* __restrict__ ei, int E, int E2,
                             int* __restrict__ counts, int* __restrict__ srcs) {
    int i = blockIdx.x * blockDim.x + threadIdx.x;
    if (i >= E2) return;
    int src, dst;
    if (i < E) { src = ei[i]; dst = ei[E + i]; }
    else       { src = i - E; dst = src; }
    srcs[i] = src;
    atomicAdd(counts + dst, 1);
}

__global__ void scan_kernel(const int* __restrict__ counts, int* __restrict__ rowptr,
                            int* __restrict__ cursor, int N) {
    __shared__ int lds[1024];
    __shared__ int base_s;
    int t = threadIdx.x;
    if (t == 0) base_s = 0;
    __syncthreads();
    for (int start = 0; start < N; start += 1024) {
        int i = start + t;
        int v = (i < N) ? counts[i] : 0;
        lds[t] = v;
        __syncthreads();
        for (int off = 1; off < 1024; off <<= 1) {
            int add = (t >= off) ? lds[t - off] : 0;
            __syncthreads();
            lds[t] += add;
            __syncthreads();
        }
        int excl = base_s + lds[t] - v;
        if (i < N) { rowptr[i] = excl; cursor[i] = excl; }
        __syncthreads();
        if (t == 0) base_s += lds[1023];
        __syncthreads();
    }
    if (t == 0) rowptr[N] = base_s;
}

__global__ void scatter_kernel(const int* __restrict__ ei, int E, int E2,
                               int* __restrict__ cursor, int* __restrict__ colidx) {
    int i = blockIdx.x * blockDim.x + threadIdx.x;
    if (i >= E2) return;
    int dst = (i < E) ? ei[E + i] : (i - E);
    int pos = atomicAdd(cursor + dst, 1);
    colidx[pos] = i;
}

// ---------------------------------------------------------------------------
// GEMM: h[N,512] = xin[N,K] @ W[K,512]; optional fused BN on xin (layer 1).
template <int K>
__global__ void gemm_kernel(const float* __restrict__ xin, const float* __restrict__ W,
                            float* __restrict__ hout, int N,
                            const float* __restrict__ scale, const float* __restrict__ shift) {
    const int BM = 32;
    __shared__ float xs[BM * K];
    int row0 = blockIdx.x * BM;
    int t = threadIdx.x;
    for (int idx = t; idx < BM * K; idx += 256) {
        int r = row0 + idx / K;
        int f = idx & (K - 1);
        float v = (r < N) ? xin[(size_t)r * K + f] : 0.f;
        if (scale) v = v * scale[f] + shift[f];
        xs[idx] = v;
    }
    __syncthreads();
    int c0 = t, c1 = t + 256;
    float acc0[BM], acc1[BM];
#pragma unroll
    for (int r = 0; r < BM; r++) { acc0[r] = 0.f; acc1[r] = 0.f; }
    for (int k = 0; k < K; k++) {
        float w0 = W[(size_t)k * HC + c0];
        float w1 = W[(size_t)k * HC + c1];
#pragma unroll
        for (int r = 0; r < BM; r++) {
            float a = xs[r * K + k];
            acc0[r] += a * w0;
            acc1[r] += a * w1;
        }
    }
    for (int r = 0; r < BM; r++) {
        int rr = row0 + r;
        if (rr < N) {
            hout[(size_t)rr * HC + c0] = acc0[r];
            hout[(size_t)rr * HC + c1] = acc1[r];
        }
    }
}

// ---------------------------------------------------------------------------
// Per-node per-head attention logits: as[n,h] = dot(h[n,h,:], a_src[h,:]), same for ad.
__global__ void asad_kernel(const float* __restrict__ hbuf, const float* __restrict__ a_src,
                            const float* __restrict__ a_dst, float* __restrict__ asv,
                            float* __restrict__ adv, int N) {
    int tid = blockIdx.x * blockDim.x + threadIdx.x;
    if (tid >= N * HEADS) return;
    int n = tid >> 3, hh = tid & 7;
    const float4* hr  = (const float4*)(hbuf + (size_t)n * HC + hh * CH);
    const float4* as4 = (const float4*)(a_src + hh * CH);
    const float4* ad4 = (const float4*)(a_dst + hh * CH);
    float sa = 0.f, sd = 0.f;
#pragma unroll
    for (int q = 0; q < 16; q++) {
        float4 hv = hr[q], av = as4[q], dv = ad4[q];
        sa += hv.x * av.x + hv.y * av.y + hv.z * av.z + hv.w * av.w;
        sd += hv.x * dv.x + hv.y * dv.y + hv.z * dv.z + hv.w * dv.w;
    }
    asv[tid] = sa;
    adv[tid] = sd;
}

// Per-edge logits e = leaky_relu(as[src] + ad[dst]) for 8 heads.
// NOTE: no pointer arithmetic across distinct locals (round-1 UB bug) — each
// float4 component is written explicitly.
__global__ void edge_logits_kernel(const int* __restrict__ ei, int E, int E2,
                                   const float* __restrict__ asv, const float* __restrict__ adv,
                                   float* __restrict__ ebuf) {
    int i = blockIdx.x * blockDim.x + threadIdx.x;
    if (i >= E2) return;
    int src, dst;
    if (i < E) { src = ei[i]; dst = ei[E + i]; }
    else       { src = i - E; dst = src; }
    const float4* a4 = (const float4*)(asv + (size_t)src * 8);
    const float4* d4 = (const float4*)(adv + (size_t)dst * 8);
    float4 s0 = a4[0], s1 = a4[1], dd0 = d4[0], dd1 = d4[1];
    float4 o0, o1;
    o0.x = lrelu(s0.x + dd0.x);
    o0.y = lrelu(s0.y + dd0.y);
    o0.z = lrelu(s0.z + dd0.z);
    o0.w = lrelu(s0.w + dd0.w);
    o1.x = lrelu(s1.x + dd1.x);
    o1.y = lrelu(s1.y + dd1.y);
    o1.z = lrelu(s1.z + dd1.z);
    o1.w = lrelu(s1.w + dd1.w);
    float4* outp = (float4*)(ebuf + (size_t)i * 8);
    outp[0] = o0;
    outp[1] = o1;
}

// Segment softmax (gather over CSR); ebuf is overwritten in-place with alpha.
__global__ void softmax_kernel(const int* __restrict__ rp, const int* __restrict__ col,
                               float* __restrict__ ebuf, int N) {
    int tid = blockIdx.x * blockDim.x + threadIdx.x;
    if (tid >= N * HEADS) return;
    int n = tid >> 3, hh = tid & 7;
    int jb = rp[n], je = rp[n + 1];
    float m = -1e30f;
    for (int j = jb; j < je; j++)
        m = fmaxf(m, ebuf[(size_t)col[j] * 8 + hh]);
    float s = 0.f;
    for (int j = jb; j < je; j++)
        s += expf(ebuf[(size_t)col[j] * 8 + hh] - m);
    float inv = 1.f / (s + 1e-16f);
    for (int j = jb; j < je; j++) {
        size_t o = (size_t)col[j] * 8 + hh;
        ebuf[o] = expf(ebuf[o] - m) * inv;
    }
}

// Aggregation gather + head mean + bias (+ optional relu): one block per dst node.
__global__ void agg_kernel(const int* __restrict__ rp, const int* __restrict__ col,
                           const int* __restrict__ srcs, const float* __restrict__ alpha,
                           const float* __restrict__ hbuf, const float* __restrict__ bias,
                           float* __restrict__ xout, int N, int dorelu) {
    int n = blockIdx.x;
    int t = threadIdx.x;
    int h0 = t >> 6, h1 = h0 + 4;
    float acc0 = 0.f, acc1 = 0.f;
    int jb = rp[n], je = rp[n + 1];
    for (int j = jb; j < je; j++) {
        int eid = col[j];
        int s = srcs[eid];
        const float* hr = hbuf + (size_t)s * HC;
        float a0 = alpha[(size_t)eid * 8 + h0];
        float a1 = alpha[(size_t)eid * 8 + h1];
        acc0 += hr[t] * a0;
        acc1 += hr[t + 256] * a1;
    }
    __shared__ float lds[HC];
    lds[t] = acc0;
    lds[t + 256] = acc1;
    __syncthreads();
    if (t < CH) {
        float s8 = 0.f;
#pragma unroll
        for (int hh = 0; hh < 8; hh++) s8 += lds[hh * CH + t];
        float v = s8 * 0.125f + bias[t];
        if (dorelu) v = fmaxf(v, 0.f);
        xout[(size_t)n * CH + t] = v;
    }
}

// ---------------------------------------------------------------------------
// global mean pool (atomic) + final linear
__global__ void pool_kernel(const float* __restrict__ x, const int* __restrict__ batch,
                            float* __restrict__ pools, float* __restrict__ pcnt, int N) {
    int tid = blockIdx.x * blockDim.x + threadIdx.x;
    if (tid >= N * CH) return;
    int n = tid >> 6, c = tid & 63;
    int g = batch[n];
    atomicAdd(pools + (size_t)g * CH + c, x[(size_t)n * CH + c]);
    if (c == 0) atomicAdd(pcnt + g, 1.f);
}

__global__ void final_kernel(const float* __restrict__ pools, const float* __restrict__ pcnt,
                             const float* __restrict__ linW, const float* __restrict__ linb,
                             float* __restrict__ out) {
    int t = threadIdx.x;
    if (t >= NGR * 2) return;
    int g = t >> 1, k = t & 1;
    float inv = 1.f / fmaxf(pcnt[g], 1.f);
    float acc = 0.f;
#pragma unroll
    for (int c = 0; c < CH; c++)
        acc += pools[(size_t)g * CH + c] * inv * linW[c * 2 + k];
    out[g * 2 + k] = acc + linb[k];
}

// ---------------------------------------------------------------------------
extern "C" void kernel_launch(void* const* d_in, const int* in_sizes, int n_in,
                              void* d_out, int out_size, void* d_ws, size_t ws_size,
                              hipStream_t stream) {
    const float* x      = (const float*)d_in[0];
    const int*   ei     = (const int*)d_in[1];
    const int*   batch  = (const int*)d_in[3];
    const float* gamma  = (const float*)d_in[4];
    const float* beta   = (const float*)d_in[5];
    const float* W1     = (const float*)d_in[6];
    const float* a1s    = (const float*)d_in[7];
    const float* a1d    = (const float*)d_in[8];
    const float* b1     = (const float*)d_in[9];
    const float* W2     = (const float*)d_in[10];
    const float* a2s    = (const float*)d_in[11];
    const float* a2d    = (const float*)d_in[12];
    const float* b2     = (const float*)d_in[13];
    const float* W3     = (const float*)d_in[14];
    const float* a3s    = (const float*)d_in[15];
    const float* a3d    = (const float*)d_in[16];
    const float* b3     = (const float*)d_in[17];
    const float* linW   = (const float*)d_in[18];
    const float* linb   = (const float*)d_in[19];
    float* out = (float*)d_out;

    const int N  = in_sizes[0] / 16;
    const int E  = in_sizes[1] / 2;
    const int E2 = E + N;

    // Workspace layout (256B aligned slices)
    char* p = (char*)d_ws;
    size_t off = 0;
    auto alloc = [&](size_t bytes) {
        void* r = p + off;
        off += (bytes + 255) & ~(size_t)255;
        return r;
    };
    float* hbuf   = (float*)alloc((size_t)N * HC * 4);
    float* xa     = (float*)alloc((size_t)N * CH * 4);
    float* xb     = (float*)alloc((size_t)N * CH * 4);
    float* asv    = (float*)alloc((size_t)N * HEADS * 4);
    float* adv    = (float*)alloc((size_t)N * HEADS * 4);
    float* ebuf   = (float*)alloc((size_t)E2 * HEADS * 4);
    float* stats  = (float*)alloc(64 * 4);
    float* pools  = (float*)alloc((size_t)NGR * CH * 4);
    float* pcnt   = (float*)alloc(NGR * 4);
    int*   rowptr = (int*)alloc((size_t)(N + 1) * 4);
    int*   cursor = (int*)alloc((size_t)N * 4);
    int*   counts = (int*)alloc((size_t)N * 4);
    int*   colidx = (int*)alloc((size_t)E2 * 4);
    int*   srcs   = (int*)alloc((size_t)E2 * 4);
    (void)ws_size;

    const int TB = 256;
    int gE2 = (E2 + TB - 1) / TB;
    int gNH = (N * HEADS + TB - 1) / TB;
    int gNC = (N * CH + TB - 1) / TB;
    int gGm = (N + 31) / 32;

    // zero-init accumulators
    hipMemsetAsync(stats, 0, 64 * 4, stream);
    hipMemsetAsync(counts, 0, (size_t)N * 4, stream);
    hipMemsetAsync(pools, 0, (size_t)NGR * CH * 4, stream);
    hipMemsetAsync(pcnt, 0, NGR * 4, stream);

    // BN statistics
    bn_stats_kernel<<<120, TB, 0, stream>>>(x, stats, N);
    bn_finalize_kernel<<<1, 32, 0, stream>>>(stats, gamma, beta, N);

    // CSR over dst
    count_kernel<<<gE2, TB, 0, stream>>>(ei, E, E2, counts, srcs);
    scan_kernel<<<1, 1024, 0, stream>>>(counts, rowptr, cursor, N);
    scatter_kernel<<<gE2, TB, 0, stream>>>(ei, E, E2, cursor, colidx);

    // ---- Layer 1 (BN fused into GEMM staging) ----
    gemm_kernel<16><<<gGm, TB, 0, stream>>>(x, W1, hbuf, N, stats + 32, stats + 48);
    asad_kernel<<<gNH, TB, 0, stream>>>(hbuf, a1s, a1d, asv, adv, N);
    edge_logits_kernel<<<gE2, TB, 0, stream>>>(ei, E, E2, asv, adv, ebuf);
    softmax_kernel<<<gNH, TB, 0, stream>>>(rowptr, colidx, ebuf, N);
    agg_kernel<<<N, TB, 0, stream>>>(rowptr, colidx, srcs, ebuf, hbuf, b1, xa, N, 1);

    // ---- Layer 2 ----
    gemm_kernel<64><<<gGm, TB, 0, stream>>>(xa, W2, hbuf, N, nullptr, nullptr);
    asad_kernel<<<gNH, TB, 0, stream>>>(hbuf, a2s, a2d, asv, adv, N);
    edge_logits_kernel<<<gE2, TB, 0, stream>>>(ei, E, E2, asv, adv, ebuf);
    softmax_kernel<<<gNH, TB, 0, stream>>>(rowptr, colidx, ebuf, N);
    agg_kernel<<<N, TB, 0, stream>>>(rowptr, colidx, srcs, ebuf, hbuf, b2, xb, N, 1);

    // ---- Layer 3 ----
    gemm_kernel<64><<<gGm, TB, 0, stream>>>(xb, W3, hbuf, N, nullptr, nullptr);
    asad_kernel<<<gNH, TB, 0, stream>>>(hbuf, a3s, a3d, asv, adv, N);
    edge_logits_kernel<<<gE2, TB, 0, stream>>>(ei, E, E2, asv, adv, ebuf);
    softmax_kernel<<<gNH, TB, 0, stream>>>(rowptr, colidx, ebuf, N);
    agg_kernel<<<N, TB, 0, stream>>>(rowptr, colidx, srcs, ebuf, hbuf, b3, xa, N, 0);

    // ---- Pool + final linear ----
    pool_kernel<<<gNC, TB, 0, stream>>>(xa, batch, pools, pcnt, N);
    final_kernel<<<1, 128, 0, stream>>>(pools, pcnt, linW, linb, out);
}

// Round 3
// 987.850 us; speedup vs baseline: 1.4822x; 1.4822x over previous
//
#include <hip/hip_runtime.h>
#include <hip/hip_bf16.h>

// Problem constants
#define HEADS 8
#define CH    64
#define HC    512   // HEADS*CH
#define NGR   64
#define NEGS  0.2f

__device__ __forceinline__ float lrelu(float v) {
    return (v > 0.f) ? v : NEGS * v;
}

// ---------------------------------------------------------------------------
// BN stats: per-feature sum / sumsq over N rows (16 features)
__global__ void bn_stats_kernel(const float* __restrict__ x, float* __restrict__ stats, int N) {
    int t0 = blockIdx.x * blockDim.x + threadIdx.x;
    int stride = gridDim.x * blockDim.x;
    float s[16], q[16];
#pragma unroll
    for (int i = 0; i < 16; i++) { s[i] = 0.f; q[i] = 0.f; }
    for (int r = t0; r < N; r += stride) {
        const float4* xr = (const float4*)(x + (size_t)r * 16);
#pragma unroll
        for (int i = 0; i < 4; i++) {
            float4 v = xr[i];
            s[4*i+0] += v.x; q[4*i+0] += v.x * v.x;
            s[4*i+1] += v.y; q[4*i+1] += v.y * v.y;
            s[4*i+2] += v.z; q[4*i+2] += v.z * v.z;
            s[4*i+3] += v.w; q[4*i+3] += v.w * v.w;
        }
    }
#pragma unroll
    for (int k = 0; k < 16; k++) {
        float vs = s[k], vq = q[k];
        for (int off = 32; off; off >>= 1) {
            vs += __shfl_down(vs, off);
            vq += __shfl_down(vq, off);
        }
        if ((threadIdx.x & 63) == 0) {
            atomicAdd(stats + k, vs);
            atomicAdd(stats + 16 + k, vq);
        }
    }
}

// stats[32..47] = scale, stats[48..63] = shift
__global__ void bn_finalize_kernel(float* __restrict__ stats,
                                   const float* __restrict__ gamma,
                                   const float* __restrict__ beta, int N) {
    int t = threadIdx.x;
    if (t < 16) {
        float invn = 1.f / (float)N;
        float mean = stats[t] * invn;
        float var  = stats[16 + t] * invn - mean * mean;
        float sc   = gamma[t] * rsqrtf(var + 1e-5f);
        stats[32 + t] = sc;
        stats[48 + t] = beta[t] - mean * sc;
    }
}

// ---------------------------------------------------------------------------
// CSR build over dst (edges + self loops). E2 = E + N.
__global__ void count_kernel(const int* __restrict__ ei, int E, int E2,
                             int* __restrict__ counts) {
    int i = blockIdx.x * blockDim.x + threadIdx.x;
    if (i >= E2) return;
    int dst = (i < E) ? ei[E + i] : (i - E);
    atomicAdd(counts + dst, 1);
}

// Single-block hierarchical scan: wave shuffle-scan + wave-sum scan (2 barriers/chunk).
__global__ void scan_kernel(const int* __restrict__ counts, int* __restrict__ rowptr,
                            int* __restrict__ cursor, int N) {
    __shared__ int wsum[16];
    __shared__ int base_s;
    int t = threadIdx.x;
    int lane = t & 63, wid = t >> 6;
    if (t == 0) base_s = 0;
    __syncthreads();
    for (int start = 0; start < N; start += 1024) {
        int i = start + t;
        int orig = (i < N) ? counts[i] : 0;
        int v = orig;
#pragma unroll
        for (int off = 1; off < 64; off <<= 1) {
            int u = __shfl_up(v, off);
            if (lane >= off) v += u;
        }
        if (lane == 63) wsum[wid] = v;
        __syncthreads();
        if (t < 16) {
            int w = wsum[t];
#pragma unroll
            for (int off = 1; off < 16; off <<= 1) {
                int u = __shfl_up(w, off);
                if (t >= off) w += u;
            }
            wsum[t] = w;
        }
        __syncthreads();
        int incl = v + (wid ? wsum[wid - 1] : 0);
        int excl = base_s + incl - orig;
        if (i < N) { rowptr[i] = excl; cursor[i] = excl; }
        __syncthreads();
        if (t == 0) base_s += wsum[15];
        __syncthreads();
    }
    if (t == 0) rowptr[N] = base_s;
}

// Scatter edge srcs into CSR order directly.
__global__ void scatter_kernel(const int* __restrict__ ei, int E, int E2,
                               int* __restrict__ cursor, int* __restrict__ src_csr) {
    int i = blockIdx.x * blockDim.x + threadIdx.x;
    if (i >= E2) return;
    int src, dst;
    if (i < E) { src = ei[i]; dst = ei[E + i]; }
    else       { src = i - E; dst = src; }
    int pos = atomicAdd(cursor + dst, 1);
    src_csr[pos] = src;
}

// ---------------------------------------------------------------------------
// GEMM: h[N,512] = xin[N,K] @ W[K,512]; optional fused BN on xin (layer 1).
template <int K>
__global__ void gemm_kernel(const float* __restrict__ xin, const float* __restrict__ W,
                            float* __restrict__ hout, int N,
                            const float* __restrict__ scale, const float* __restrict__ shift) {
    const int BM = 32;
    __shared__ float xs[BM * K];
    int row0 = blockIdx.x * BM;
    int t = threadIdx.x;
    for (int idx = t; idx < BM * K; idx += 256) {
        int r = row0 + idx / K;
        int f = idx & (K - 1);
        float v = (r < N) ? xin[(size_t)r * K + f] : 0.f;
        if (scale) v = v * scale[f] + shift[f];
        xs[idx] = v;
    }
    __syncthreads();
    int c0 = t, c1 = t + 256;
    float acc0[BM], acc1[BM];
#pragma unroll
    for (int r = 0; r < BM; r++) { acc0[r] = 0.f; acc1[r] = 0.f; }
    for (int k = 0; k < K; k++) {
        float w0 = W[(size_t)k * HC + c0];
        float w1 = W[(size_t)k * HC + c1];
#pragma unroll
        for (int r = 0; r < BM; r++) {
            float a = xs[r * K + k];
            acc0[r] += a * w0;
            acc1[r] += a * w1;
        }
    }
    for (int r = 0; r < BM; r++) {
        int rr = row0 + r;
        if (rr < N) {
            hout[(size_t)rr * HC + c0] = acc0[r];
            hout[(size_t)rr * HC + c1] = acc1[r];
        }
    }
}

// ---------------------------------------------------------------------------
// Per-node per-head attention logits: as[n,h] = dot(h[n,h,:], a_src[h,:]), same for ad.
__global__ void asad_kernel(const float* __restrict__ hbuf, const float* __restrict__ a_src,
                            const float* __restrict__ a_dst, float* __restrict__ asv,
                            float* __restrict__ adv, int N) {
    int tid = blockIdx.x * blockDim.x + threadIdx.x;
    if (tid >= N * HEADS) return;
    int n = tid >> 3, hh = tid & 7;
    const float4* hr  = (const float4*)(hbuf + (size_t)n * HC + hh * CH);
    const float4* as4 = (const float4*)(a_src + hh * CH);
    const float4* ad4 = (const float4*)(a_dst + hh * CH);
    float sa = 0.f, sd = 0.f;
#pragma unroll
    for (int q = 0; q < 16; q++) {
        float4 hv = hr[q], av = as4[q], dv = ad4[q];
        sa += hv.x * av.x + hv.y * av.y + hv.z * av.z + hv.w * av.w;
        sd += hv.x * dv.x + hv.y * dv.y + hv.z * dv.z + hv.w * dv.w;
    }
    asv[tid] = sa;
    adv[tid] = sd;
}

// ---------------------------------------------------------------------------
// Fused edge-logits + segment softmax, node-parallel over CSR.
// Thread = (node, head). Writes alpha in CSR order.
__global__ void softmax_kernel(const int* __restrict__ rp, const int* __restrict__ src_csr,
                               const float* __restrict__ asv, const float* __restrict__ adv,
                               float* __restrict__ alpha_csr, int N) {
    int tid = blockIdx.x * blockDim.x + threadIdx.x;
    if (tid >= N * HEADS) return;
    int n = tid >> 3, hh = tid & 7;
    int jb = rp[n], je = rp[n + 1];
    float ad = adv[(size_t)n * 8 + hh];
    float m = -1e30f;
    for (int j = jb; j < je; j++) {
        float e = lrelu(asv[(size_t)src_csr[j] * 8 + hh] + ad);
        m = fmaxf(m, e);
    }
    float s = 0.f;
    for (int j = jb; j < je; j++) {
        float e = lrelu(asv[(size_t)src_csr[j] * 8 + hh] + ad);
        float ex = expf(e - m);
        alpha_csr[(size_t)j * 8 + hh] = ex;
        s += ex;
    }
    float inv = 1.f / (s + 1e-16f);
    for (int j = jb; j < je; j++)
        alpha_csr[(size_t)j * 8 + hh] *= inv;
}

// ---------------------------------------------------------------------------
// Aggregation: one WAVE per dst node. Lane l owns output channel l across all
// 8 heads (8 fp32 accumulators) — no LDS, no cross-lane reduce.
// Per edge: 8 coalesced 256B loads of h[src] + 2 broadcast float4 alpha loads.
__global__ void agg_kernel(const int* __restrict__ rp, const int* __restrict__ src_csr,
                           const float* __restrict__ alpha_csr,
                           const float* __restrict__ hbuf, const float* __restrict__ bias,
                           float* __restrict__ xout, int N, int dorelu) {
    int gw = (blockIdx.x * blockDim.x + threadIdx.x) >> 6;  // global wave id = node
    int lane = threadIdx.x & 63;
    if (gw >= N) return;
    int jb = rp[gw], je = rp[gw + 1];
    float a0 = 0.f, a1 = 0.f, a2 = 0.f, a3 = 0.f;
    float a4 = 0.f, a5 = 0.f, a6 = 0.f, a7 = 0.f;
    int j = jb;
    for (; j + 2 <= je; j += 2) {
        int s0 = src_csr[j], s1 = src_csr[j + 1];
        const float4* ap0 = (const float4*)(alpha_csr + (size_t)j * 8);
        float4 w00 = ap0[0], w01 = ap0[1];
        const float4* ap1 = (const float4*)(alpha_csr + (size_t)(j + 1) * 8);
        float4 w10 = ap1[0], w11 = ap1[1];
        const float* h0 = hbuf + (size_t)s0 * HC + lane;
        const float* h1 = hbuf + (size_t)s1 * HC + lane;
        float v00 = h0[0],   v01 = h0[64],  v02 = h0[128], v03 = h0[192];
        float v04 = h0[256], v05 = h0[320], v06 = h0[384], v07 = h0[448];
        float v10 = h1[0],   v11 = h1[64],  v12 = h1[128], v13 = h1[192];
        float v14 = h1[256], v15 = h1[320], v16 = h1[384], v17 = h1[448];
        a0 += w00.x * v00; a1 += w00.y * v01; a2 += w00.z * v02; a3 += w00.w * v03;
        a4 += w01.x * v04; a5 += w01.y * v05; a6 += w01.z * v06; a7 += w01.w * v07;
        a0 += w10.x * v10; a1 += w10.y * v11; a2 += w10.z * v12; a3 += w10.w * v13;
        a4 += w11.x * v14; a5 += w11.y * v15; a6 += w11.z * v16; a7 += w11.w * v17;
    }
    for (; j < je; j++) {
        int s0 = src_csr[j];
        const float4* ap0 = (const float4*)(alpha_csr + (size_t)j * 8);
        float4 w00 = ap0[0], w01 = ap0[1];
        const float* h0 = hbuf + (size_t)s0 * HC + lane;
        a0 += w00.x * h0[0];   a1 += w00.y * h0[64];
        a2 += w00.z * h0[128]; a3 += w00.w * h0[192];
        a4 += w01.x * h0[256]; a5 += w01.y * h0[320];
        a6 += w01.z * h0[384]; a7 += w01.w * h0[448];
    }
    float v = (a0 + a1 + a2 + a3 + a4 + a5 + a6 + a7) * 0.125f + bias[lane];
    if (dorelu) v = fmaxf(v, 0.f);
    xout[(size_t)gw * CH + lane] = v;
}

// ---------------------------------------------------------------------------
// Pool: batch is sorted -> contiguous node chunks, run-local accumulation,
// one atomic flush per (block, graph-boundary) instead of per element.
__global__ void pool_kernel(const float* __restrict__ x, const int* __restrict__ batch,
                            float* __restrict__ pools, float* __restrict__ pcnt,
                            int N, int chunk) {
    int c  = threadIdx.x & 63;
    int nl = threadIdx.x >> 6;   // 0..3
    int n0 = blockIdx.x * chunk;
    int n1 = min(n0 + chunk, N);
    float acc = 0.f, cnt = 0.f;
    int curg = -1;
    for (int n = n0 + nl; n < n1; n += 4) {
        int g = batch[n];
        if (g != curg) {
            if (curg >= 0) {
                atomicAdd(pools + (size_t)curg * CH + c, acc);
                if (c == 0) atomicAdd(pcnt + curg, cnt);
            }
            curg = g; acc = 0.f; cnt = 0.f;
        }
        acc += x[(size_t)n * CH + c];
        cnt += 1.f;
    }
    if (curg >= 0) {
        atomicAdd(pools + (size_t)curg * CH + c, acc);
        if (c == 0) atomicAdd(pcnt + curg, cnt);
    }
}

__global__ void final_kernel(const float* __restrict__ pools, const float* __restrict__ pcnt,
                             const float* __restrict__ linW, const float* __restrict__ linb,
                             float* __restrict__ out) {
    int t = threadIdx.x;
    if (t >= NGR * 2) return;
    int g = t >> 1, k = t & 1;
    float inv = 1.f / fmaxf(pcnt[g], 1.f);
    float acc = 0.f;
#pragma unroll
    for (int c = 0; c < CH; c++)
        acc += pools[(size_t)g * CH + c] * inv * linW[c * 2 + k];
    out[g * 2 + k] = acc + linb[k];
}

// ---------------------------------------------------------------------------
extern "C" void kernel_launch(void* const* d_in, const int* in_sizes, int n_in,
                              void* d_out, int out_size, void* d_ws, size_t ws_size,
                              hipStream_t stream) {
    const float* x      = (const float*)d_in[0];
    const int*   ei     = (const int*)d_in[1];
    const int*   batch  = (const int*)d_in[3];
    const float* gamma  = (const float*)d_in[4];
    const float* beta   = (const float*)d_in[5];
    const float* W1     = (const float*)d_in[6];
    const float* a1s    = (const float*)d_in[7];
    const float* a1d    = (const float*)d_in[8];
    const float* b1     = (const float*)d_in[9];
    const float* W2     = (const float*)d_in[10];
    const float* a2s    = (const float*)d_in[11];
    const float* a2d    = (const float*)d_in[12];
    const float* b2     = (const float*)d_in[13];
    const float* W3     = (const float*)d_in[14];
    const float* a3s    = (const float*)d_in[15];
    const float* a3d    = (const float*)d_in[16];
    const float* b3     = (const float*)d_in[17];
    const float* linW   = (const float*)d_in[18];
    const float* linb   = (const float*)d_in[19];
    float* out = (float*)d_out;

    const int N  = in_sizes[0] / 16;
    const int E  = in_sizes[1] / 2;
    const int E2 = E + N;

    // Workspace layout (256B aligned slices)
    char* p = (char*)d_ws;
    size_t off = 0;
    auto alloc = [&](size_t bytes) {
        void* r = p + off;
        off += (bytes + 255) & ~(size_t)255;
        return r;
    };
    float* hbuf      = (float*)alloc((size_t)N * HC * 4);
    float* xa        = (float*)alloc((size_t)N * CH * 4);
    float* xb        = (float*)alloc((size_t)N * CH * 4);
    float* asv       = (float*)alloc((size_t)N * HEADS * 4);
    float* adv       = (float*)alloc((size_t)N * HEADS * 4);
    float* alpha_csr = (float*)alloc((size_t)E2 * HEADS * 4);
    float* stats     = (float*)alloc(64 * 4);
    float* pools     = (float*)alloc((size_t)NGR * CH * 4);
    float* pcnt      = (float*)alloc(NGR * 4);
    int*   rowptr    = (int*)alloc((size_t)(N + 1) * 4);
    int*   cursor    = (int*)alloc((size_t)N * 4);
    int*   counts    = (int*)alloc((size_t)N * 4);
    int*   src_csr   = (int*)alloc((size_t)E2 * 4);
    (void)ws_size;

    const int TB = 256;
    int gE2 = (E2 + TB - 1) / TB;
    int gNH = (N * HEADS + TB - 1) / TB;
    int gGm = (N + 31) / 32;
    int gAg = (N * 64 + TB - 1) / TB;      // one wave per node
    const int PCHUNK = 256;
    int gPool = (N + PCHUNK - 1) / PCHUNK;

    // zero-init accumulators
    hipMemsetAsync(stats, 0, 64 * 4, stream);
    hipMemsetAsync(counts, 0, (size_t)N * 4, stream);
    hipMemsetAsync(pools, 0, (size_t)NGR * CH * 4, stream);
    hipMemsetAsync(pcnt, 0, NGR * 4, stream);

    // BN statistics
    bn_stats_kernel<<<120, TB, 0, stream>>>(x, stats, N);
    bn_finalize_kernel<<<1, 32, 0, stream>>>(stats, gamma, beta, N);

    // CSR over dst
    count_kernel<<<gE2, TB, 0, stream>>>(ei, E, E2, counts);
    scan_kernel<<<1, 1024, 0, stream>>>(counts, rowptr, cursor, N);
    scatter_kernel<<<gE2, TB, 0, stream>>>(ei, E, E2, cursor, src_csr);

    // ---- Layer 1 (BN fused into GEMM staging) ----
    gemm_kernel<16><<<gGm, TB, 0, stream>>>(x, W1, hbuf, N, stats + 32, stats + 48);
    asad_kernel<<<gNH, TB, 0, stream>>>(hbuf, a1s, a1d, asv, adv, N);
    softmax_kernel<<<gNH, TB, 0, stream>>>(rowptr, src_csr, asv, adv, alpha_csr, N);
    agg_kernel<<<gAg, TB, 0, stream>>>(rowptr, src_csr, alpha_csr, hbuf, b1, xa, N, 1);

    // ---- Layer 2 ----
    gemm_kernel<64><<<gGm, TB, 0, stream>>>(xa, W2, hbuf, N, nullptr, nullptr);
    asad_kernel<<<gNH, TB, 0, stream>>>(hbuf, a2s, a2d, asv, adv, N);
    softmax_kernel<<<gNH, TB, 0, stream>>>(rowptr, src_csr, asv, adv, alpha_csr, N);
    agg_kernel<<<gAg, TB, 0, stream>>>(rowptr, src_csr, alpha_csr, hbuf, b2, xb, N, 1);

    // ---- Layer 3 ----
    gemm_kernel<64><<<gGm, TB, 0, stream>>>(xb, W3, hbuf, N, nullptr, nullptr);
    asad_kernel<<<gNH, TB, 0, stream>>>(hbuf, a3s, a3d, asv, adv, N);
    softmax_kernel<<<gNH, TB, 0, stream>>>(rowptr, src_csr, asv, adv, alpha_csr, N);
    agg_kernel<<<gAg, TB, 0, stream>>>(rowptr, src_csr, alpha_csr, hbuf, b3, xa, N, 0);

    // ---- Pool + final linear ----
    pool_kernel<<<gPool, TB, 0, stream>>>(xa, batch, pools, pcnt, N, PCHUNK);
    final_kernel<<<1, 128, 0, stream>>>(pools, pcnt, linW, linb, out);
}

// Round 4
// 909.771 us; speedup vs baseline: 1.6094x; 1.0858x over previous
//
#include <hip/hip_runtime.h>
#include <hip/hip_bf16.h>

// Problem constants
#define HEADS 8
#define CH    64
#define HC    512   // HEADS*CH
#define NGR   64
#define NEGS  0.2f

__device__ __forceinline__ float lrelu(float v) {
    return (v > 0.f) ? v : NEGS * v;
}

// ---------------------------------------------------------------------------
// BN stats: per-feature sum / sumsq over N rows (16 features)
__global__ void bn_stats_kernel(const float* __restrict__ x, float* __restrict__ stats, int N) {
    int t0 = blockIdx.x * blockDim.x + threadIdx.x;
    int stride = gridDim.x * blockDim.x;
    float s[16], q[16];
#pragma unroll
    for (int i = 0; i < 16; i++) { s[i] = 0.f; q[i] = 0.f; }
    for (int r = t0; r < N; r += stride) {
        const float4* xr = (const float4*)(x + (size_t)r * 16);
#pragma unroll
        for (int i = 0; i < 4; i++) {
            float4 v = xr[i];
            s[4*i+0] += v.x; q[4*i+0] += v.x * v.x;
            s[4*i+1] += v.y; q[4*i+1] += v.y * v.y;
            s[4*i+2] += v.z; q[4*i+2] += v.z * v.z;
            s[4*i+3] += v.w; q[4*i+3] += v.w * v.w;
        }
    }
#pragma unroll
    for (int k = 0; k < 16; k++) {
        float vs = s[k], vq = q[k];
        for (int off = 32; off; off >>= 1) {
            vs += __shfl_down(vs, off);
            vq += __shfl_down(vq, off);
        }
        if ((threadIdx.x & 63) == 0) {
            atomicAdd(stats + k, vs);
            atomicAdd(stats + 16 + k, vq);
        }
    }
}

// stats[32..47] = scale, stats[48..63] = shift
__global__ void bn_finalize_kernel(float* __restrict__ stats,
                                   const float* __restrict__ gamma,
                                   const float* __restrict__ beta, int N) {
    int t = threadIdx.x;
    if (t < 16) {
        float invn = 1.f / (float)N;
        float mean = stats[t] * invn;
        float var  = stats[16 + t] * invn - mean * mean;
        float sc   = gamma[t] * rsqrtf(var + 1e-5f);
        stats[32 + t] = sc;
        stats[48 + t] = beta[t] - mean * sc;
    }
}

// ---------------------------------------------------------------------------
// CSR build over dst (edges + self loops). E2 = E + N.
__global__ void count_kernel(const int* __restrict__ ei, int E, int E2,
                             int* __restrict__ counts) {
    int i = blockIdx.x * blockDim.x + threadIdx.x;
    if (i >= E2) return;
    int dst = (i < E) ? ei[E + i] : (i - E);
    atomicAdd(counts + dst, 1);
}

// Single-block scan, 4 elems/thread (int4): 8 chunk iterations for N=30000.
__global__ void scan_kernel(const int* __restrict__ counts, int* __restrict__ rowptr,
                            int* __restrict__ cursor, int N) {
    __shared__ int wsum[16];
    __shared__ int base_s;
    int t = threadIdx.x;
    int lane = t & 63, wid = t >> 6;
    if (t == 0) base_s = 0;
    __syncthreads();
    for (int start = 0; start < N; start += 4096) {
        int i0 = start + t * 4;
        int e0 = 0, e1 = 0, e2 = 0, e3 = 0;
        if (i0 + 3 < N) {
            const int4 c4 = *(const int4*)(counts + i0);
            e0 = c4.x; e1 = c4.y; e2 = c4.z; e3 = c4.w;
        } else {
            if (i0 + 0 < N) e0 = counts[i0 + 0];
            if (i0 + 1 < N) e1 = counts[i0 + 1];
            if (i0 + 2 < N) e2 = counts[i0 + 2];
            if (i0 + 3 < N) e3 = counts[i0 + 3];
        }
        int tot = e0 + e1 + e2 + e3;
        int v = tot;
#pragma unroll
        for (int off = 1; off < 64; off <<= 1) {
            int u = __shfl_up(v, off);
            if (lane >= off) v += u;
        }
        if (lane == 63) wsum[wid] = v;
        __syncthreads();
        if (t < 16) {
            int w = wsum[t];
#pragma unroll
            for (int off = 1; off < 16; off <<= 1) {
                int u = __shfl_up(w, off);
                if (t >= off) w += u;
            }
            wsum[t] = w;
        }
        __syncthreads();
        int excl = base_s + (v - tot) + (wid ? wsum[wid - 1] : 0);
        int p0 = excl, p1 = p0 + e0, p2 = p1 + e1, p3 = p2 + e2;
        if (i0 + 3 < N) {
            *(int4*)(rowptr + i0) = make_int4(p0, p1, p2, p3);
            *(int4*)(cursor + i0) = make_int4(p0, p1, p2, p3);
        } else {
            if (i0 + 0 < N) { rowptr[i0 + 0] = p0; cursor[i0 + 0] = p0; }
            if (i0 + 1 < N) { rowptr[i0 + 1] = p1; cursor[i0 + 1] = p1; }
            if (i0 + 2 < N) { rowptr[i0 + 2] = p2; cursor[i0 + 2] = p2; }
            if (i0 + 3 < N) { rowptr[i0 + 3] = p3; cursor[i0 + 3] = p3; }
        }
        __syncthreads();
        if (t == 0) base_s += wsum[15];
        __syncthreads();
    }
    if (t == 0) rowptr[N] = base_s;
}

// Scatter edge srcs into CSR order directly.
__global__ void scatter_kernel(const int* __restrict__ ei, int E, int E2,
                               int* __restrict__ cursor, int* __restrict__ src_csr) {
    int i = blockIdx.x * blockDim.x + threadIdx.x;
    if (i >= E2) return;
    int src, dst;
    if (i < E) { src = ei[i]; dst = ei[E + i]; }
    else       { src = i - E; dst = src; }
    int pos = atomicAdd(cursor + dst, 1);
    src_csr[pos] = src;
}

// ---------------------------------------------------------------------------
// GEMM: h[N,512] = xin[N,K] @ W[K,512]; optional fused BN on xin (layer 1).
template <int K>
__global__ void gemm_kernel(const float* __restrict__ xin, const float* __restrict__ W,
                            float* __restrict__ hout, int N,
                            const float* __restrict__ scale, const float* __restrict__ shift) {
    const int BM = 32;
    __shared__ float xs[BM * K];
    int row0 = blockIdx.x * BM;
    int t = threadIdx.x;
    for (int idx = t; idx < BM * K; idx += 256) {
        int r = row0 + idx / K;
        int f = idx & (K - 1);
        float v = (r < N) ? xin[(size_t)r * K + f] : 0.f;
        if (scale) v = v * scale[f] + shift[f];
        xs[idx] = v;
    }
    __syncthreads();
    int c0 = t, c1 = t + 256;
    float acc0[BM], acc1[BM];
#pragma unroll
    for (int r = 0; r < BM; r++) { acc0[r] = 0.f; acc1[r] = 0.f; }
    for (int k = 0; k < K; k++) {
        float w0 = W[(size_t)k * HC + c0];
        float w1 = W[(size_t)k * HC + c1];
#pragma unroll
        for (int r = 0; r < BM; r++) {
            float a = xs[r * K + k];
            acc0[r] += a * w0;
            acc1[r] += a * w1;
        }
    }
    for (int r = 0; r < BM; r++) {
        int rr = row0 + r;
        if (rr < N) {
            hout[(size_t)rr * HC + c0] = acc0[r];
            hout[(size_t)rr * HC + c1] = acc1[r];
        }
    }
}

// ---------------------------------------------------------------------------
// Per-node per-head attention logits: as[n,h] = dot(h[n,h,:], a_src[h,:]), same for ad.
__global__ void asad_kernel(const float* __restrict__ hbuf, const float* __restrict__ a_src,
                            const float* __restrict__ a_dst, float* __restrict__ asv,
                            float* __restrict__ adv, int N) {
    int tid = blockIdx.x * blockDim.x + threadIdx.x;
    if (tid >= N * HEADS) return;
    int n = tid >> 3, hh = tid & 7;
    const float4* hr  = (const float4*)(hbuf + (size_t)n * HC + hh * CH);
    const float4* as4 = (const float4*)(a_src + hh * CH);
    const float4* ad4 = (const float4*)(a_dst + hh * CH);
    float sa = 0.f, sd = 0.f;
#pragma unroll
    for (int q = 0; q < 16; q++) {
        float4 hv = hr[q], av = as4[q], dv = ad4[q];
        sa += hv.x * av.x + hv.y * av.y + hv.z * av.z + hv.w * av.w;
        sd += hv.x * dv.x + hv.y * dv.y + hv.z * dv.z + hv.w * dv.w;
    }
    asv[tid] = sa;
    adv[tid] = sd;
}

// ---------------------------------------------------------------------------
// Fused softmax + aggregation: one WAVE per dst node, single pass over edges.
// No max-subtraction (logits O(1) here; shift cancels in normalization).
// Lane l: float4 at row+4l (head h0=l>>4, ch (l&15)*4..+3) and row+256+4l
// (head h0+4). Accumulates Σ exp(e)·h and Σ exp(e) per head; normalizes,
// head-means, cross-lane reduces, and 16 lanes store float4.
__global__ void agg_kernel(const int* __restrict__ rp, const int* __restrict__ src_csr,
                           const float* __restrict__ asv, const float* __restrict__ adv,
                           const float* __restrict__ hbuf, const float* __restrict__ bias,
                           float* __restrict__ xout, int N, int dorelu) {
    int gw = (blockIdx.x * blockDim.x + threadIdx.x) >> 6;  // node id
    int lane = threadIdx.x & 63;
    if (gw >= N) return;
    int h0 = lane >> 4;           // head for low half (h0+4 for high half)
    int cofs = 4 * lane;          // element offset of the float4 within row
    int jb = rp[gw], je = rp[gw + 1];
    float adA = adv[(size_t)gw * 8 + h0];
    float adB = adv[(size_t)gw * 8 + h0 + 4];
    float accA0 = 0.f, accA1 = 0.f, accA2 = 0.f, accA3 = 0.f;
    float accB0 = 0.f, accB1 = 0.f, accB2 = 0.f, accB3 = 0.f;
    float denA = 0.f, denB = 0.f;
    int j = jb;
    for (; j + 2 <= je; j += 2) {
        int s0 = src_csr[j], s1 = src_csr[j + 1];
        float as0A = asv[(size_t)s0 * 8 + h0];
        float as0B = asv[(size_t)s0 * 8 + h0 + 4];
        float as1A = asv[(size_t)s1 * 8 + h0];
        float as1B = asv[(size_t)s1 * 8 + h0 + 4];
        const float* r0 = hbuf + (size_t)s0 * HC + cofs;
        const float* r1 = hbuf + (size_t)s1 * HC + cofs;
        float4 v0A = *(const float4*)(r0);
        float4 v0B = *(const float4*)(r0 + 256);
        float4 v1A = *(const float4*)(r1);
        float4 v1B = *(const float4*)(r1 + 256);
        float e0A = __expf(lrelu(as0A + adA));
        float e0B = __expf(lrelu(as0B + adB));
        float e1A = __expf(lrelu(as1A + adA));
        float e1B = __expf(lrelu(as1B + adB));
        denA += e0A + e1A;
        denB += e0B + e1B;
        accA0 += e0A * v0A.x; accA1 += e0A * v0A.y; accA2 += e0A * v0A.z; accA3 += e0A * v0A.w;
        accB0 += e0B * v0B.x; accB1 += e0B * v0B.y; accB2 += e0B * v0B.z; accB3 += e0B * v0B.w;
        accA0 += e1A * v1A.x; accA1 += e1A * v1A.y; accA2 += e1A * v1A.z; accA3 += e1A * v1A.w;
        accB0 += e1B * v1B.x; accB1 += e1B * v1B.y; accB2 += e1B * v1B.z; accB3 += e1B * v1B.w;
    }
    for (; j < je; j++) {
        int s0 = src_csr[j];
        float as0A = asv[(size_t)s0 * 8 + h0];
        float as0B = asv[(size_t)s0 * 8 + h0 + 4];
        const float* r0 = hbuf + (size_t)s0 * HC + cofs;
        float4 v0A = *(const float4*)(r0);
        float4 v0B = *(const float4*)(r0 + 256);
        float e0A = __expf(lrelu(as0A + adA));
        float e0B = __expf(lrelu(as0B + adB));
        denA += e0A;
        denB += e0B;
        accA0 += e0A * v0A.x; accA1 += e0A * v0A.y; accA2 += e0A * v0A.z; accA3 += e0A * v0A.w;
        accB0 += e0B * v0B.x; accB1 += e0B * v0B.y; accB2 += e0B * v0B.z; accB3 += e0B * v0B.w;
    }
    float rA = 1.f / (denA + 1e-16f);
    float rB = 1.f / (denB + 1e-16f);
    float t0 = accA0 * rA + accB0 * rB;
    float t1 = accA1 * rA + accB1 * rB;
    float t2 = accA2 * rA + accB2 * rB;
    float t3 = accA3 * rA + accB3 * rB;
    // sum lanes {l, l+16, l+32, l+48} -> all 8 heads at lanes 0..15
    t0 += __shfl_down(t0, 32); t1 += __shfl_down(t1, 32);
    t2 += __shfl_down(t2, 32); t3 += __shfl_down(t3, 32);
    t0 += __shfl_down(t0, 16); t1 += __shfl_down(t1, 16);
    t2 += __shfl_down(t2, 16); t3 += __shfl_down(t3, 16);
    if (lane < 16) {
        float4 bv = *(const float4*)(bias + 4 * lane);
        float4 o;
        o.x = t0 * 0.125f + bv.x;
        o.y = t1 * 0.125f + bv.y;
        o.z = t2 * 0.125f + bv.z;
        o.w = t3 * 0.125f + bv.w;
        if (dorelu) {
            o.x = fmaxf(o.x, 0.f); o.y = fmaxf(o.y, 0.f);
            o.z = fmaxf(o.z, 0.f); o.w = fmaxf(o.w, 0.f);
        }
        *(float4*)(xout + (size_t)gw * CH + 4 * lane) = o;
    }
}

// ---------------------------------------------------------------------------
// Pool: batch sorted -> run-local accumulation, atomic flush per boundary.
__global__ void pool_kernel(const float* __restrict__ x, const int* __restrict__ batch,
                            float* __restrict__ pools, float* __restrict__ pcnt,
                            int N, int chunk) {
    int c  = threadIdx.x & 63;
    int nl = threadIdx.x >> 6;   // 0..3
    int n0 = blockIdx.x * chunk;
    int n1 = min(n0 + chunk, N);
    float acc = 0.f, cnt = 0.f;
    int curg = -1;
    for (int n = n0 + nl; n < n1; n += 4) {
        int g = batch[n];
        if (g != curg) {
            if (curg >= 0) {
                atomicAdd(pools + (size_t)curg * CH + c, acc);
                if (c == 0) atomicAdd(pcnt + curg, cnt);
            }
            curg = g; acc = 0.f; cnt = 0.f;
        }
        acc += x[(size_t)n * CH + c];
        cnt += 1.f;
    }
    if (curg >= 0) {
        atomicAdd(pools + (size_t)curg * CH + c, acc);
        if (c == 0) atomicAdd(pcnt + curg, cnt);
    }
}

__global__ void final_kernel(const float* __restrict__ pools, const float* __restrict__ pcnt,
                             const float* __restrict__ linW, const float* __restrict__ linb,
                             float* __restrict__ out) {
    int t = threadIdx.x;
    if (t >= NGR * 2) return;
    int g = t >> 1, k = t & 1;
    float inv = 1.f / fmaxf(pcnt[g], 1.f);
    float acc = 0.f;
#pragma unroll
    for (int c = 0; c < CH; c++)
        acc += pools[(size_t)g * CH + c] * inv * linW[c * 2 + k];
    out[g * 2 + k] = acc + linb[k];
}

// ---------------------------------------------------------------------------
extern "C" void kernel_launch(void* const* d_in, const int* in_sizes, int n_in,
                              void* d_out, int out_size, void* d_ws, size_t ws_size,
                              hipStream_t stream) {
    const float* x      = (const float*)d_in[0];
    const int*   ei     = (const int*)d_in[1];
    const int*   batch  = (const int*)d_in[3];
    const float* gamma  = (const float*)d_in[4];
    const float* beta   = (const float*)d_in[5];
    const float* W1     = (const float*)d_in[6];
    const float* a1s    = (const float*)d_in[7];
    const float* a1d    = (const float*)d_in[8];
    const float* b1     = (const float*)d_in[9];
    const float* W2     = (const float*)d_in[10];
    const float* a2s    = (const float*)d_in[11];
    const float* a2d    = (const float*)d_in[12];
    const float* b2     = (const float*)d_in[13];
    const float* W3     = (const float*)d_in[14];
    const float* a3s    = (const float*)d_in[15];
    const float* a3d    = (const float*)d_in[16];
    const float* b3     = (const float*)d_in[17];
    const float* linW   = (const float*)d_in[18];
    const float* linb   = (const float*)d_in[19];
    float* out = (float*)d_out;

    const int N  = in_sizes[0] / 16;
    const int E  = in_sizes[1] / 2;
    const int E2 = E + N;

    // Workspace layout (256B aligned slices)
    char* p = (char*)d_ws;
    size_t off = 0;
    auto alloc = [&](size_t bytes) {
        void* r = p + off;
        off += (bytes + 255) & ~(size_t)255;
        return r;
    };
    float* hbuf    = (float*)alloc((size_t)N * HC * 4);
    float* xa      = (float*)alloc((size_t)N * CH * 4);
    float* xb      = (float*)alloc((size_t)N * CH * 4);
    float* asv     = (float*)alloc((size_t)N * HEADS * 4);
    float* adv     = (float*)alloc((size_t)N * HEADS * 4);
    float* stats   = (float*)alloc(64 * 4);
    float* pools   = (float*)alloc((size_t)NGR * CH * 4);
    float* pcnt    = (float*)alloc(NGR * 4);
    int*   rowptr  = (int*)alloc((size_t)(N + 1) * 4);
    int*   cursor  = (int*)alloc((size_t)N * 4);
    int*   counts  = (int*)alloc((size_t)N * 4);
    int*   src_csr = (int*)alloc((size_t)E2 * 4);
    (void)ws_size;

    const int TB = 256;
    int gE2 = (E2 + TB - 1) / TB;
    int gNH = (N * HEADS + TB - 1) / TB;
    int gGm = (N + 31) / 32;
    int gAg = (N * 64 + TB - 1) / TB;      // one wave per node
    const int PCHUNK = 256;
    int gPool = (N + PCHUNK - 1) / PCHUNK;

    // zero-init accumulators
    hipMemsetAsync(stats, 0, 64 * 4, stream);
    hipMemsetAsync(counts, 0, (size_t)N * 4, stream);
    hipMemsetAsync(pools, 0, (size_t)NGR * CH * 4, stream);
    hipMemsetAsync(pcnt, 0, NGR * 4, stream);

    // BN statistics
    bn_stats_kernel<<<120, TB, 0, stream>>>(x, stats, N);
    bn_finalize_kernel<<<1, 32, 0, stream>>>(stats, gamma, beta, N);

    // CSR over dst
    count_kernel<<<gE2, TB, 0, stream>>>(ei, E, E2, counts);
    scan_kernel<<<1, 1024, 0, stream>>>(counts, rowptr, cursor, N);
    scatter_kernel<<<gE2, TB, 0, stream>>>(ei, E, E2, cursor, src_csr);

    // ---- Layer 1 (BN fused into GEMM staging) ----
    gemm_kernel<16><<<gGm, TB, 0, stream>>>(x, W1, hbuf, N, stats + 32, stats + 48);
    asad_kernel<<<gNH, TB, 0, stream>>>(hbuf, a1s, a1d, asv, adv, N);
    agg_kernel<<<gAg, TB, 0, stream>>>(rowptr, src_csr, asv, adv, hbuf, b1, xa, N, 1);

    // ---- Layer 2 ----
    gemm_kernel<64><<<gGm, TB, 0, stream>>>(xa, W2, hbuf, N, nullptr, nullptr);
    asad_kernel<<<gNH, TB, 0, stream>>>(hbuf, a2s, a2d, asv, adv, N);
    agg_kernel<<<gAg, TB, 0, stream>>>(rowptr, src_csr, asv, adv, hbuf, b2, xb, N, 1);

    // ---- Layer 3 ----
    gemm_kernel<64><<<gGm, TB, 0, stream>>>(xb, W3, hbuf, N, nullptr, nullptr);
    asad_kernel<<<gNH, TB, 0, stream>>>(hbuf, a3s, a3d, asv, adv, N);
    agg_kernel<<<gAg, TB, 0, stream>>>(rowptr, src_csr, asv, adv, hbuf, b3, xa, N, 0);

    // ---- Pool + final linear ----
    pool_kernel<<<gPool, TB, 0, stream>>>(xa, batch, pools, pcnt, N, PCHUNK);
    final_kernel<<<1, 128, 0, stream>>>(pools, pcnt, linW, linb, out);
}

// Round 5
// 650.467 us; speedup vs baseline: 2.2510x; 1.3986x over previous
//
#include <hip/hip_runtime.h>
#include <hip/hip_bf16.h>

// Problem constants
#define HEADS 8
#define CH    64
#define HC    512   // HEADS*CH
#define NGR   64
#define NEGS  0.2f

__device__ __forceinline__ float lrelu(float v) {
    return (v > 0.f) ? v : NEGS * v;
}

// bf16 (as ushort) -> fp32
__device__ __forceinline__ float bf2f_lo(unsigned u) { return __uint_as_float(u << 16); }
__device__ __forceinline__ float bf2f_hi(unsigned u) { return __uint_as_float(u & 0xffff0000u); }

// ---------------------------------------------------------------------------
// BN stats: per-feature sum / sumsq over N rows (16 features)
__global__ void bn_stats_kernel(const float* __restrict__ x, float* __restrict__ stats, int N) {
    int t0 = blockIdx.x * blockDim.x + threadIdx.x;
    int stride = gridDim.x * blockDim.x;
    float s[16], q[16];
#pragma unroll
    for (int i = 0; i < 16; i++) { s[i] = 0.f; q[i] = 0.f; }
    for (int r = t0; r < N; r += stride) {
        const float4* xr = (const float4*)(x + (size_t)r * 16);
#pragma unroll
        for (int i = 0; i < 4; i++) {
            float4 v = xr[i];
            s[4*i+0] += v.x; q[4*i+0] += v.x * v.x;
            s[4*i+1] += v.y; q[4*i+1] += v.y * v.y;
            s[4*i+2] += v.z; q[4*i+2] += v.z * v.z;
            s[4*i+3] += v.w; q[4*i+3] += v.w * v.w;
        }
    }
#pragma unroll
    for (int k = 0; k < 16; k++) {
        float vs = s[k], vq = q[k];
        for (int off = 32; off; off >>= 1) {
            vs += __shfl_down(vs, off);
            vq += __shfl_down(vq, off);
        }
        if ((threadIdx.x & 63) == 0) {
            atomicAdd(stats + k, vs);
            atomicAdd(stats + 16 + k, vq);
        }
    }
}

// stats[32..47] = scale, stats[48..63] = shift
__global__ void bn_finalize_kernel(float* __restrict__ stats,
                                   const float* __restrict__ gamma,
                                   const float* __restrict__ beta, int N) {
    int t = threadIdx.x;
    if (t < 16) {
        float invn = 1.f / (float)N;
        float mean = stats[t] * invn;
        float var  = stats[16 + t] * invn - mean * mean;
        float sc   = gamma[t] * rsqrtf(var + 1e-5f);
        stats[32 + t] = sc;
        stats[48 + t] = beta[t] - mean * sc;
    }
}

// ---------------------------------------------------------------------------
// CSR build over dst (edges + self loops). E2 = E + N.
__global__ void count_kernel(const int* __restrict__ ei, int E, int E2,
                             int* __restrict__ counts) {
    int i = blockIdx.x * blockDim.x + threadIdx.x;
    if (i >= E2) return;
    int dst = (i < E) ? ei[E + i] : (i - E);
    atomicAdd(counts + dst, 1);
}

// Single-block scan, 4 elems/thread (int4).
__global__ void scan_kernel(const int* __restrict__ counts, int* __restrict__ rowptr,
                            int* __restrict__ cursor, int N) {
    __shared__ int wsum[16];
    __shared__ int base_s;
    int t = threadIdx.x;
    int lane = t & 63, wid = t >> 6;
    if (t == 0) base_s = 0;
    __syncthreads();
    for (int start = 0; start < N; start += 4096) {
        int i0 = start + t * 4;
        int e0 = 0, e1 = 0, e2 = 0, e3 = 0;
        if (i0 + 3 < N) {
            const int4 c4 = *(const int4*)(counts + i0);
            e0 = c4.x; e1 = c4.y; e2 = c4.z; e3 = c4.w;
        } else {
            if (i0 + 0 < N) e0 = counts[i0 + 0];
            if (i0 + 1 < N) e1 = counts[i0 + 1];
            if (i0 + 2 < N) e2 = counts[i0 + 2];
            if (i0 + 3 < N) e3 = counts[i0 + 3];
        }
        int tot = e0 + e1 + e2 + e3;
        int v = tot;
#pragma unroll
        for (int off = 1; off < 64; off <<= 1) {
            int u = __shfl_up(v, off);
            if (lane >= off) v += u;
        }
        if (lane == 63) wsum[wid] = v;
        __syncthreads();
        if (t < 16) {
            int w = wsum[t];
#pragma unroll
            for (int off = 1; off < 16; off <<= 1) {
                int u = __shfl_up(w, off);
                if (t >= off) w += u;
            }
            wsum[t] = w;
        }
        __syncthreads();
        int excl = base_s + (v - tot) + (wid ? wsum[wid - 1] : 0);
        int p0 = excl, p1 = p0 + e0, p2 = p1 + e1, p3 = p2 + e2;
        if (i0 + 3 < N) {
            *(int4*)(rowptr + i0) = make_int4(p0, p1, p2, p3);
            *(int4*)(cursor + i0) = make_int4(p0, p1, p2, p3);
        } else {
            if (i0 + 0 < N) { rowptr[i0 + 0] = p0; cursor[i0 + 0] = p0; }
            if (i0 + 1 < N) { rowptr[i0 + 1] = p1; cursor[i0 + 1] = p1; }
            if (i0 + 2 < N) { rowptr[i0 + 2] = p2; cursor[i0 + 2] = p2; }
            if (i0 + 3 < N) { rowptr[i0 + 3] = p3; cursor[i0 + 3] = p3; }
        }
        __syncthreads();
        if (t == 0) base_s += wsum[15];
        __syncthreads();
    }
    if (t == 0) rowptr[N] = base_s;
}

// Scatter edge (src,dst) into CSR order.
__global__ void scatter_kernel(const int* __restrict__ ei, int E, int E2,
                               int* __restrict__ cursor,
                               int* __restrict__ src_csr, int* __restrict__ dst_csr) {
    int i = blockIdx.x * blockDim.x + threadIdx.x;
    if (i >= E2) return;
    int src, dst;
    if (i < E) { src = ei[i]; dst = ei[E + i]; }
    else       { src = i - E; dst = src; }
    int pos = atomicAdd(cursor + dst, 1);
    src_csr[pos] = src;
    dst_csr[pos] = dst;
}

// ---------------------------------------------------------------------------
// GEMM: h[N,512](bf16) = xin[N,K](fp32) @ W[K,512]; optional fused BN (layer 1).
template <int K>
__global__ void gemm_kernel(const float* __restrict__ xin, const float* __restrict__ W,
                            __hip_bfloat16* __restrict__ hout, int N,
                            const float* __restrict__ scale, const float* __restrict__ shift) {
    const int BM = 32;
    __shared__ float xs[BM * K];
    int row0 = blockIdx.x * BM;
    int t = threadIdx.x;
    for (int idx = t; idx < BM * K; idx += 256) {
        int r = row0 + idx / K;
        int f = idx & (K - 1);
        float v = (r < N) ? xin[(size_t)r * K + f] : 0.f;
        if (scale) v = v * scale[f] + shift[f];
        xs[idx] = v;
    }
    __syncthreads();
    int c0 = t, c1 = t + 256;
    float acc0[BM], acc1[BM];
#pragma unroll
    for (int r = 0; r < BM; r++) { acc0[r] = 0.f; acc1[r] = 0.f; }
    for (int k = 0; k < K; k++) {
        float w0 = W[(size_t)k * HC + c0];
        float w1 = W[(size_t)k * HC + c1];
#pragma unroll
        for (int r = 0; r < BM; r++) {
            float a = xs[r * K + k];
            acc0[r] += a * w0;
            acc1[r] += a * w1;
        }
    }
    for (int r = 0; r < BM; r++) {
        int rr = row0 + r;
        if (rr < N) {
            hout[(size_t)rr * HC + c0] = __float2bfloat16(acc0[r]);
            hout[(size_t)rr * HC + c1] = __float2bfloat16(acc1[r]);
        }
    }
}

// ---------------------------------------------------------------------------
// asad: one wave per node. Lane l holds bf16 elements 8l..8l+7 of the row
// (head l>>3, 8 channels); a_src/a_dst are flat at the same offsets.
// Reduce within 8-lane groups (xor 1,2,4); lane h*8 writes head h.
__global__ void asad_kernel(const ushort* __restrict__ hbuf, const float* __restrict__ a_src,
                            const float* __restrict__ a_dst, float* __restrict__ asv,
                            float* __restrict__ adv, int N) {
    int gw = (blockIdx.x * blockDim.x + threadIdx.x) >> 6;
    int lane = threadIdx.x & 63;
    if (gw >= N) return;
    uint4 p = *(const uint4*)(hbuf + (size_t)gw * HC + 8 * lane);
    float h0 = bf2f_lo(p.x), h1 = bf2f_hi(p.x);
    float h2 = bf2f_lo(p.y), h3 = bf2f_hi(p.y);
    float h4 = bf2f_lo(p.z), h5 = bf2f_hi(p.z);
    float h6 = bf2f_lo(p.w), h7 = bf2f_hi(p.w);
    const float4* s4 = (const float4*)(a_src + 8 * lane);
    const float4* d4 = (const float4*)(a_dst + 8 * lane);
    float4 sa0 = s4[0], sa1 = s4[1];
    float4 da0 = d4[0], da1 = d4[1];
    float sa = h0*sa0.x + h1*sa0.y + h2*sa0.z + h3*sa0.w
             + h4*sa1.x + h5*sa1.y + h6*sa1.z + h7*sa1.w;
    float sd = h0*da0.x + h1*da0.y + h2*da0.z + h3*da0.w
             + h4*da1.x + h5*da1.y + h6*da1.z + h7*da1.w;
    sa += __shfl_xor(sa, 1); sa += __shfl_xor(sa, 2); sa += __shfl_xor(sa, 4);
    sd += __shfl_xor(sd, 1); sd += __shfl_xor(sd, 2); sd += __shfl_xor(sd, 4);
    if ((lane & 7) == 0) {
        asv[(size_t)gw * 8 + (lane >> 3)] = sa;
        adv[(size_t)gw * 8 + (lane >> 3)] = sd;
    }
}

// ---------------------------------------------------------------------------
// Unnormalized attention weights in CSR order: alpha[j][h] = exp(lrelu(...)).
// One-pass (no max subtraction — logits are O(1); shift cancels in the
// normalization done by agg).
__global__ void alpha_kernel(const int* __restrict__ src_csr, const int* __restrict__ dst_csr,
                             const float* __restrict__ asv, const float* __restrict__ adv,
                             float* __restrict__ alpha_csr, int E2) {
    int tid = blockIdx.x * blockDim.x + threadIdx.x;
    if (tid >= E2 * 8) return;
    int j = tid >> 3, h = tid & 7;
    int s = src_csr[j], d = dst_csr[j];
    float e = lrelu(asv[(size_t)s * 8 + h] + adv[(size_t)d * 8 + h]);
    alpha_csr[tid] = __expf(e);
}

// ---------------------------------------------------------------------------
// Aggregation: one WAVE per dst node, PURE gather+FMA loop.
// Lane l: one uint4 (8 bf16) of h[src] (head l>>3, channels 8(l&7)..+7) and
// one fp32 weight. Wave accumulates its own softmax denominator.
__global__ void agg_kernel(const int* __restrict__ rp, const int* __restrict__ src_csr,
                           const float* __restrict__ alpha_csr,
                           const ushort* __restrict__ hbuf, const float* __restrict__ bias,
                           float* __restrict__ xout, int N, int dorelu) {
    int gw = (blockIdx.x * blockDim.x + threadIdx.x) >> 6;  // node id
    int lane = threadIdx.x & 63;
    if (gw >= N) return;
    int head = lane >> 3;
    size_t lofs = 8 * (size_t)lane;
    int jb = rp[gw], je = rp[gw + 1];
    float acc[8];
#pragma unroll
    for (int r = 0; r < 8; r++) acc[r] = 0.f;
    float den = 0.f;
    int j = jb;
    for (; j + 2 <= je; j += 2) {
        int s0 = src_csr[j], s1 = src_csr[j + 1];
        float w0 = alpha_csr[(size_t)j * 8 + head];
        float w1 = alpha_csr[(size_t)(j + 1) * 8 + head];
        uint4 p0 = *(const uint4*)(hbuf + (size_t)s0 * HC + lofs);
        uint4 p1 = *(const uint4*)(hbuf + (size_t)s1 * HC + lofs);
        den += w0 + w1;
        acc[0] += w0 * bf2f_lo(p0.x); acc[1] += w0 * bf2f_hi(p0.x);
        acc[2] += w0 * bf2f_lo(p0.y); acc[3] += w0 * bf2f_hi(p0.y);
        acc[4] += w0 * bf2f_lo(p0.z); acc[5] += w0 * bf2f_hi(p0.z);
        acc[6] += w0 * bf2f_lo(p0.w); acc[7] += w0 * bf2f_hi(p0.w);
        acc[0] += w1 * bf2f_lo(p1.x); acc[1] += w1 * bf2f_hi(p1.x);
        acc[2] += w1 * bf2f_lo(p1.y); acc[3] += w1 * bf2f_hi(p1.y);
        acc[4] += w1 * bf2f_lo(p1.z); acc[5] += w1 * bf2f_hi(p1.z);
        acc[6] += w1 * bf2f_lo(p1.w); acc[7] += w1 * bf2f_hi(p1.w);
    }
    for (; j < je; j++) {
        int s0 = src_csr[j];
        float w0 = alpha_csr[(size_t)j * 8 + head];
        uint4 p0 = *(const uint4*)(hbuf + (size_t)s0 * HC + lofs);
        den += w0;
        acc[0] += w0 * bf2f_lo(p0.x); acc[1] += w0 * bf2f_hi(p0.x);
        acc[2] += w0 * bf2f_lo(p0.y); acc[3] += w0 * bf2f_hi(p0.y);
        acc[4] += w0 * bf2f_lo(p0.z); acc[5] += w0 * bf2f_hi(p0.z);
        acc[6] += w0 * bf2f_lo(p0.w); acc[7] += w0 * bf2f_hi(p0.w);
    }
    float inv = 1.f / (den + 1e-16f);
#pragma unroll
    for (int r = 0; r < 8; r++) {
        acc[r] *= inv;
        acc[r] += __shfl_xor(acc[r], 8);
        acc[r] += __shfl_xor(acc[r], 16);
        acc[r] += __shfl_xor(acc[r], 32);
    }
    if (lane < 8) {
        const float4* b4 = (const float4*)(bias + 8 * lane);
        float4 bv0 = b4[0], bv1 = b4[1];
        float4 o0, o1;
        o0.x = acc[0] * 0.125f + bv0.x;
        o0.y = acc[1] * 0.125f + bv0.y;
        o0.z = acc[2] * 0.125f + bv0.z;
        o0.w = acc[3] * 0.125f + bv0.w;
        o1.x = acc[4] * 0.125f + bv1.x;
        o1.y = acc[5] * 0.125f + bv1.y;
        o1.z = acc[6] * 0.125f + bv1.z;
        o1.w = acc[7] * 0.125f + bv1.w;
        if (dorelu) {
            o0.x = fmaxf(o0.x, 0.f); o0.y = fmaxf(o0.y, 0.f);
            o0.z = fmaxf(o0.z, 0.f); o0.w = fmaxf(o0.w, 0.f);
            o1.x = fmaxf(o1.x, 0.f); o1.y = fmaxf(o1.y, 0.f);
            o1.z = fmaxf(o1.z, 0.f); o1.w = fmaxf(o1.w, 0.f);
        }
        float4* op = (float4*)(xout + (size_t)gw * CH + 8 * lane);
        op[0] = o0;
        op[1] = o1;
    }
}

// ---------------------------------------------------------------------------
// Pool: batch sorted -> run-local accumulation, atomic flush per boundary.
__global__ void pool_kernel(const float* __restrict__ x, const int* __restrict__ batch,
                            float* __restrict__ pools, float* __restrict__ pcnt,
                            int N, int chunk) {
    int c  = threadIdx.x & 63;
    int nl = threadIdx.x >> 6;   // 0..3
    int n0 = blockIdx.x * chunk;
    int n1 = min(n0 + chunk, N);
    float acc = 0.f, cnt = 0.f;
    int curg = -1;
    for (int n = n0 + nl; n < n1; n += 4) {
        int g = batch[n];
        if (g != curg) {
            if (curg >= 0) {
                atomicAdd(pools + (size_t)curg * CH + c, acc);
                if (c == 0) atomicAdd(pcnt + curg, cnt);
            }
            curg = g; acc = 0.f; cnt = 0.f;
        }
        acc += x[(size_t)n * CH + c];
        cnt += 1.f;
    }
    if (curg >= 0) {
        atomicAdd(pools + (size_t)curg * CH + c, acc);
        if (c == 0) atomicAdd(pcnt + curg, cnt);
    }
}

__global__ void final_kernel(const float* __restrict__ pools, const float* __restrict__ pcnt,
                             const float* __restrict__ linW, const float* __restrict__ linb,
                             float* __restrict__ out) {
    int t = threadIdx.x;
    if (t >= NGR * 2) return;
    int g = t >> 1, k = t & 1;
    float inv = 1.f / fmaxf(pcnt[g], 1.f);
    float acc = 0.f;
#pragma unroll
    for (int c = 0; c < CH; c++)
        acc += pools[(size_t)g * CH + c] * inv * linW[c * 2 + k];
    out[g * 2 + k] = acc + linb[k];
}

// ---------------------------------------------------------------------------
extern "C" void kernel_launch(void* const* d_in, const int* in_sizes, int n_in,
                              void* d_out, int out_size, void* d_ws, size_t ws_size,
                              hipStream_t stream) {
    const float* x      = (const float*)d_in[0];
    const int*   ei     = (const int*)d_in[1];
    const int*   batch  = (const int*)d_in[3];
    const float* gamma  = (const float*)d_in[4];
    const float* beta   = (const float*)d_in[5];
    const float* W1     = (const float*)d_in[6];
    const float* a1s    = (const float*)d_in[7];
    const float* a1d    = (const float*)d_in[8];
    const float* b1     = (const float*)d_in[9];
    const float* W2     = (const float*)d_in[10];
    const float* a2s    = (const float*)d_in[11];
    const float* a2d    = (const float*)d_in[12];
    const float* b2     = (const float*)d_in[13];
    const float* W3     = (const float*)d_in[14];
    const float* a3s    = (const float*)d_in[15];
    const float* a3d    = (const float*)d_in[16];
    const float* b3     = (const float*)d_in[17];
    const float* linW   = (const float*)d_in[18];
    const float* linb   = (const float*)d_in[19];
    float* out = (float*)d_out;

    const int N  = in_sizes[0] / 16;
    const int E  = in_sizes[1] / 2;
    const int E2 = E + N;

    // Workspace layout (256B aligned slices)
    char* p = (char*)d_ws;
    size_t off = 0;
    auto alloc = [&](size_t bytes) {
        void* r = p + off;
        off += (bytes + 255) & ~(size_t)255;
        return r;
    };
    __hip_bfloat16* hbuf = (__hip_bfloat16*)alloc((size_t)N * HC * 2);
    float* xa        = (float*)alloc((size_t)N * CH * 4);
    float* xb        = (float*)alloc((size_t)N * CH * 4);
    float* asv       = (float*)alloc((size_t)N * HEADS * 4);
    float* adv       = (float*)alloc((size_t)N * HEADS * 4);
    float* alpha_csr = (float*)alloc((size_t)E2 * HEADS * 4);
    float* stats     = (float*)alloc(64 * 4);
    float* pools     = (float*)alloc((size_t)NGR * CH * 4);
    float* pcnt      = (float*)alloc(NGR * 4);
    int*   rowptr    = (int*)alloc((size_t)(N + 1) * 4);
    int*   cursor    = (int*)alloc((size_t)N * 4);
    int*   counts    = (int*)alloc((size_t)N * 4);
    int*   src_csr   = (int*)alloc((size_t)E2 * 4);
    int*   dst_csr   = (int*)alloc((size_t)E2 * 4);
    (void)ws_size;

    const int TB = 256;
    int gE2 = (E2 + TB - 1) / TB;
    int gEH = (E2 * 8 + TB - 1) / TB;
    int gGm = (N + 31) / 32;
    int gWv = (N * 64 + TB - 1) / TB;      // one wave per node
    const int PCHUNK = 256;
    int gPool = (N + PCHUNK - 1) / PCHUNK;

    const ushort* hb = (const ushort*)hbuf;

    // zero-init accumulators
    hipMemsetAsync(stats, 0, 64 * 4, stream);
    hipMemsetAsync(counts, 0, (size_t)N * 4, stream);
    hipMemsetAsync(pools, 0, (size_t)NGR * CH * 4, stream);
    hipMemsetAsync(pcnt, 0, NGR * 4, stream);

    // BN statistics
    bn_stats_kernel<<<120, TB, 0, stream>>>(x, stats, N);
    bn_finalize_kernel<<<1, 32, 0, stream>>>(stats, gamma, beta, N);

    // CSR over dst
    count_kernel<<<gE2, TB, 0, stream>>>(ei, E, E2, counts);
    scan_kernel<<<1, 1024, 0, stream>>>(counts, rowptr, cursor, N);
    scatter_kernel<<<gE2, TB, 0, stream>>>(ei, E, E2, cursor, src_csr, dst_csr);

    // ---- Layer 1 (BN fused into GEMM staging) ----
    gemm_kernel<16><<<gGm, TB, 0, stream>>>(x, W1, hbuf, N, stats + 32, stats + 48);
    asad_kernel<<<gWv, TB, 0, stream>>>(hb, a1s, a1d, asv, adv, N);
    alpha_kernel<<<gEH, TB, 0, stream>>>(src_csr, dst_csr, asv, adv, alpha_csr, E2);
    agg_kernel<<<gWv, TB, 0, stream>>>(rowptr, src_csr, alpha_csr, hb, b1, xa, N, 1);

    // ---- Layer 2 ----
    gemm_kernel<64><<<gGm, TB, 0, stream>>>(xa, W2, hbuf, N, nullptr, nullptr);
    asad_kernel<<<gWv, TB, 0, stream>>>(hb, a2s, a2d, asv, adv, N);
    alpha_kernel<<<gEH, TB, 0, stream>>>(src_csr, dst_csr, asv, adv, alpha_csr, E2);
    agg_kernel<<<gWv, TB, 0, stream>>>(rowptr, src_csr, alpha_csr, hb, b2, xb, N, 1);

    // ---- Layer 3 ----
    gemm_kernel<64><<<gGm, TB, 0, stream>>>(xb, W3, hbuf, N, nullptr, nullptr);
    asad_kernel<<<gWv, TB, 0, stream>>>(hb, a3s, a3d, asv, adv, N);
    alpha_kernel<<<gEH, TB, 0, stream>>>(src_csr, dst_csr, asv, adv, alpha_csr, E2);
    agg_kernel<<<gWv, TB, 0, stream>>>(rowptr, src_csr, alpha_csr, hb, b3, xa, N, 0);

    // ---- Pool + final linear ----
    pool_kernel<<<gPool, TB, 0, stream>>>(xa, batch, pools, pcnt, N, PCHUNK);
    final_kernel<<<1, 128, 0, stream>>>(pools, pcnt, linW, linb, out);
}

// Round 6
// 567.447 us; speedup vs baseline: 2.5803x; 1.1463x over previous
//
#include <hip/hip_runtime.h>
#include <hip/hip_bf16.h>

// Problem constants
#define HEADS 8
#define CH    64
#define HC    512   // HEADS*CH
#define NGR   64
#define NEGS  0.2f
#define BNB   60    // bn_stats blocks

__device__ __forceinline__ float lrelu(float v) {
    return (v > 0.f) ? v : NEGS * v;
}

// bf16 (as ushort) -> fp32
__device__ __forceinline__ float bf2f_lo(unsigned u) { return __uint_as_float(u << 16); }
__device__ __forceinline__ float bf2f_hi(unsigned u) { return __uint_as_float(u & 0xffff0000u); }

// ---------------------------------------------------------------------------
// BN stats stage 1: per-block partial sum/sumsq over 16 features, NO atomics.
// partials[block][0..15]=sum, [16..31]=sumsq.
__global__ void bn_stats_kernel(const float* __restrict__ x, float* __restrict__ partials,
                                int N, int chunk) {
    int n0 = blockIdx.x * chunk;
    int n1 = min(n0 + chunk, N);
    float s[16], q[16];
#pragma unroll
    for (int i = 0; i < 16; i++) { s[i] = 0.f; q[i] = 0.f; }
    for (int r = n0 + threadIdx.x; r < n1; r += 256) {
        const float4* xr = (const float4*)(x + (size_t)r * 16);
#pragma unroll
        for (int i = 0; i < 4; i++) {
            float4 v = xr[i];
            s[4*i+0] += v.x; q[4*i+0] += v.x * v.x;
            s[4*i+1] += v.y; q[4*i+1] += v.y * v.y;
            s[4*i+2] += v.z; q[4*i+2] += v.z * v.z;
            s[4*i+3] += v.w; q[4*i+3] += v.w * v.w;
        }
    }
    // wave-level reduce each of the 32 values to lane 0
#pragma unroll
    for (int k = 0; k < 16; k++) {
#pragma unroll
        for (int off = 32; off; off >>= 1) {
            s[k] += __shfl_down(s[k], off);
            q[k] += __shfl_down(q[k], off);
        }
    }
    __shared__ float lds[4][32];
    int lane = threadIdx.x & 63, wid = threadIdx.x >> 6;
    if (lane == 0) {
#pragma unroll
        for (int k = 0; k < 16; k++) { lds[wid][k] = s[k]; lds[wid][16 + k] = q[k]; }
    }
    __syncthreads();
    int t = threadIdx.x;
    if (t < 32) {
        float v = lds[0][t] + lds[1][t] + lds[2][t] + lds[3][t];
        partials[(size_t)blockIdx.x * 32 + t] = v;
    }
}

// BN stage 2: reduce partials; stats[32..47]=scale, stats[48..63]=shift.
__global__ void bn_finalize_kernel(const float* __restrict__ partials, float* __restrict__ stats,
                                   const float* __restrict__ gamma,
                                   const float* __restrict__ beta, int N, int nblk) {
    __shared__ float sums[32];
    int t = threadIdx.x;
    if (t < 32) {
        float v = 0.f;
        for (int b = 0; b < nblk; b++) v += partials[(size_t)b * 32 + t];
        sums[t] = v;
    }
    __syncthreads();
    if (t < 16) {
        float invn = 1.f / (float)N;
        float mean = sums[t] * invn;
        float var  = sums[16 + t] * invn - mean * mean;
        float sc   = gamma[t] * rsqrtf(var + 1e-5f);
        stats[32 + t] = sc;
        stats[48 + t] = beta[t] - mean * sc;
    }
}

// ---------------------------------------------------------------------------
// CSR build over dst (edges + self loops). E2 = E + N.
__global__ void count_kernel(const int* __restrict__ ei, int E, int E2,
                             int* __restrict__ counts) {
    int i = blockIdx.x * blockDim.x + threadIdx.x;
    if (i >= E2) return;
    int dst = (i < E) ? ei[E + i] : (i - E);
    atomicAdd(counts + dst, 1);
}

// Single-block scan, 4 elems/thread (int4).
__global__ void scan_kernel(const int* __restrict__ counts, int* __restrict__ rowptr,
                            int* __restrict__ cursor, int N) {
    __shared__ int wsum[16];
    __shared__ int base_s;
    int t = threadIdx.x;
    int lane = t & 63, wid = t >> 6;
    if (t == 0) base_s = 0;
    __syncthreads();
    for (int start = 0; start < N; start += 4096) {
        int i0 = start + t * 4;
        int e0 = 0, e1 = 0, e2 = 0, e3 = 0;
        if (i0 + 3 < N) {
            const int4 c4 = *(const int4*)(counts + i0);
            e0 = c4.x; e1 = c4.y; e2 = c4.z; e3 = c4.w;
        } else {
            if (i0 + 0 < N) e0 = counts[i0 + 0];
            if (i0 + 1 < N) e1 = counts[i0 + 1];
            if (i0 + 2 < N) e2 = counts[i0 + 2];
            if (i0 + 3 < N) e3 = counts[i0 + 3];
        }
        int tot = e0 + e1 + e2 + e3;
        int v = tot;
#pragma unroll
        for (int off = 1; off < 64; off <<= 1) {
            int u = __shfl_up(v, off);
            if (lane >= off) v += u;
        }
        if (lane == 63) wsum[wid] = v;
        __syncthreads();
        if (t < 16) {
            int w = wsum[t];
#pragma unroll
            for (int off = 1; off < 16; off <<= 1) {
                int u = __shfl_up(w, off);
                if (t >= off) w += u;
            }
            wsum[t] = w;
        }
        __syncthreads();
        int excl = base_s + (v - tot) + (wid ? wsum[wid - 1] : 0);
        int p0 = excl, p1 = p0 + e0, p2 = p1 + e1, p3 = p2 + e2;
        if (i0 + 3 < N) {
            *(int4*)(rowptr + i0) = make_int4(p0, p1, p2, p3);
            *(int4*)(cursor + i0) = make_int4(p0, p1, p2, p3);
        } else {
            if (i0 + 0 < N) { rowptr[i0 + 0] = p0; cursor[i0 + 0] = p0; }
            if (i0 + 1 < N) { rowptr[i0 + 1] = p1; cursor[i0 + 1] = p1; }
            if (i0 + 2 < N) { rowptr[i0 + 2] = p2; cursor[i0 + 2] = p2; }
            if (i0 + 3 < N) { rowptr[i0 + 3] = p3; cursor[i0 + 3] = p3; }
        }
        __syncthreads();
        if (t == 0) base_s += wsum[15];
        __syncthreads();
    }
    if (t == 0) rowptr[N] = base_s;
}

// Scatter edge (src,dst) into CSR order.
__global__ void scatter_kernel(const int* __restrict__ ei, int E, int E2,
                               int* __restrict__ cursor,
                               int* __restrict__ src_csr, int* __restrict__ dst_csr) {
    int i = blockIdx.x * blockDim.x + threadIdx.x;
    if (i >= E2) return;
    int src, dst;
    if (i < E) { src = ei[i]; dst = ei[E + i]; }
    else       { src = i - E; dst = src; }
    int pos = atomicAdd(cursor + dst, 1);
    src_csr[pos] = src;
    dst_csr[pos] = dst;
}

// ---------------------------------------------------------------------------
// GEMM: h[N,512](bf16) = xin[N,K](fp32) @ W[K,512]; optional fused BN (layer 1).
template <int K>
__global__ void gemm_kernel(const float* __restrict__ xin, const float* __restrict__ W,
                            __hip_bfloat16* __restrict__ hout, int N,
                            const float* __restrict__ scale, const float* __restrict__ shift) {
    const int BM = 32;
    __shared__ float xs[BM * K];
    int row0 = blockIdx.x * BM;
    int t = threadIdx.x;
    for (int idx = t; idx < BM * K; idx += 256) {
        int r = row0 + idx / K;
        int f = idx & (K - 1);
        float v = (r < N) ? xin[(size_t)r * K + f] : 0.f;
        if (scale) v = v * scale[f] + shift[f];
        xs[idx] = v;
    }
    __syncthreads();
    int c0 = t, c1 = t + 256;
    float acc0[BM], acc1[BM];
#pragma unroll
    for (int r = 0; r < BM; r++) { acc0[r] = 0.f; acc1[r] = 0.f; }
    for (int k = 0; k < K; k++) {
        float w0 = W[(size_t)k * HC + c0];
        float w1 = W[(size_t)k * HC + c1];
#pragma unroll
        for (int r = 0; r < BM; r++) {
            float a = xs[r * K + k];
            acc0[r] += a * w0;
            acc1[r] += a * w1;
        }
    }
    for (int r = 0; r < BM; r++) {
        int rr = row0 + r;
        if (rr < N) {
            hout[(size_t)rr * HC + c0] = __float2bfloat16(acc0[r]);
            hout[(size_t)rr * HC + c1] = __float2bfloat16(acc1[r]);
        }
    }
}

// ---------------------------------------------------------------------------
// asad: one wave per node. Lane l holds bf16 elements 8l..8l+7 of the row
// (head l>>3, 8 channels); reduce within 8-lane groups; lane h*8 writes head h.
__global__ void asad_kernel(const ushort* __restrict__ hbuf, const float* __restrict__ a_src,
                            const float* __restrict__ a_dst, float* __restrict__ asv,
                            float* __restrict__ adv, int N) {
    int gw = (blockIdx.x * blockDim.x + threadIdx.x) >> 6;
    int lane = threadIdx.x & 63;
    if (gw >= N) return;
    uint4 p = *(const uint4*)(hbuf + (size_t)gw * HC + 8 * lane);
    float h0 = bf2f_lo(p.x), h1 = bf2f_hi(p.x);
    float h2 = bf2f_lo(p.y), h3 = bf2f_hi(p.y);
    float h4 = bf2f_lo(p.z), h5 = bf2f_hi(p.z);
    float h6 = bf2f_lo(p.w), h7 = bf2f_hi(p.w);
    const float4* s4 = (const float4*)(a_src + 8 * lane);
    const float4* d4 = (const float4*)(a_dst + 8 * lane);
    float4 sa0 = s4[0], sa1 = s4[1];
    float4 da0 = d4[0], da1 = d4[1];
    float sa = h0*sa0.x + h1*sa0.y + h2*sa0.z + h3*sa0.w
             + h4*sa1.x + h5*sa1.y + h6*sa1.z + h7*sa1.w;
    float sd = h0*da0.x + h1*da0.y + h2*da0.z + h3*da0.w
             + h4*da1.x + h5*da1.y + h6*da1.z + h7*da1.w;
    sa += __shfl_xor(sa, 1); sa += __shfl_xor(sa, 2); sa += __shfl_xor(sa, 4);
    sd += __shfl_xor(sd, 1); sd += __shfl_xor(sd, 2); sd += __shfl_xor(sd, 4);
    if ((lane & 7) == 0) {
        asv[(size_t)gw * 8 + (lane >> 3)] = sa;
        adv[(size_t)gw * 8 + (lane >> 3)] = sd;
    }
}

// ---------------------------------------------------------------------------
// Unnormalized attention weights in CSR order: alpha[j][h] = exp(lrelu(...)).
__global__ void alpha_kernel(const int* __restrict__ src_csr, const int* __restrict__ dst_csr,
                             const float* __restrict__ asv, const float* __restrict__ adv,
                             float* __restrict__ alpha_csr, int E2) {
    int tid = blockIdx.x * blockDim.x + threadIdx.x;
    if (tid >= E2 * 8) return;
    int j = tid >> 3, h = tid & 7;
    int s = src_csr[j], d = dst_csr[j];
    float e = lrelu(asv[(size_t)s * 8 + h] + adv[(size_t)d * 8 + h]);
    alpha_csr[tid] = __expf(e);
}

// ---------------------------------------------------------------------------
// Aggregation: one WAVE per dst node, PURE gather+FMA loop.
// Lane l: one uint4 (8 bf16) of h[src] (head l>>3, channels 8(l&7)..+7) and
// one fp32 weight. Wave accumulates its own softmax denominator.
__global__ void agg_kernel(const int* __restrict__ rp, const int* __restrict__ src_csr,
                           const float* __restrict__ alpha_csr,
                           const ushort* __restrict__ hbuf, const float* __restrict__ bias,
                           float* __restrict__ xout, int N, int dorelu) {
    int gw = (blockIdx.x * blockDim.x + threadIdx.x) >> 6;  // node id
    int lane = threadIdx.x & 63;
    if (gw >= N) return;
    int head = lane >> 3;
    size_t lofs = 8 * (size_t)lane;
    int jb = rp[gw], je = rp[gw + 1];
    float acc[8];
#pragma unroll
    for (int r = 0; r < 8; r++) acc[r] = 0.f;
    float den = 0.f;
    int j = jb;
    for (; j + 2 <= je; j += 2) {
        int s0 = src_csr[j], s1 = src_csr[j + 1];
        float w0 = alpha_csr[(size_t)j * 8 + head];
        float w1 = alpha_csr[(size_t)(j + 1) * 8 + head];
        uint4 p0 = *(const uint4*)(hbuf + (size_t)s0 * HC + lofs);
        uint4 p1 = *(const uint4*)(hbuf + (size_t)s1 * HC + lofs);
        den += w0 + w1;
        acc[0] += w0 * bf2f_lo(p0.x); acc[1] += w0 * bf2f_hi(p0.x);
        acc[2] += w0 * bf2f_lo(p0.y); acc[3] += w0 * bf2f_hi(p0.y);
        acc[4] += w0 * bf2f_lo(p0.z); acc[5] += w0 * bf2f_hi(p0.z);
        acc[6] += w0 * bf2f_lo(p0.w); acc[7] += w0 * bf2f_hi(p0.w);
        acc[0] += w1 * bf2f_lo(p1.x); acc[1] += w1 * bf2f_hi(p1.x);
        acc[2] += w1 * bf2f_lo(p1.y); acc[3] += w1 * bf2f_hi(p1.y);
        acc[4] += w1 * bf2f_lo(p1.z); acc[5] += w1 * bf2f_hi(p1.z);
        acc[6] += w1 * bf2f_lo(p1.w); acc[7] += w1 * bf2f_hi(p1.w);
    }
    for (; j < je; j++) {
        int s0 = src_csr[j];
        float w0 = alpha_csr[(size_t)j * 8 + head];
        uint4 p0 = *(const uint4*)(hbuf + (size_t)s0 * HC + lofs);
        den += w0;
        acc[0] += w0 * bf2f_lo(p0.x); acc[1] += w0 * bf2f_hi(p0.x);
        acc[2] += w0 * bf2f_lo(p0.y); acc[3] += w0 * bf2f_hi(p0.y);
        acc[4] += w0 * bf2f_lo(p0.z); acc[5] += w0 * bf2f_hi(p0.z);
        acc[6] += w0 * bf2f_lo(p0.w); acc[7] += w0 * bf2f_hi(p0.w);
    }
    float inv = 1.f / (den + 1e-16f);
#pragma unroll
    for (int r = 0; r < 8; r++) {
        acc[r] *= inv;
        acc[r] += __shfl_xor(acc[r], 8);
        acc[r] += __shfl_xor(acc[r], 16);
        acc[r] += __shfl_xor(acc[r], 32);
    }
    if (lane < 8) {
        const float4* b4 = (const float4*)(bias + 8 * lane);
        float4 bv0 = b4[0], bv1 = b4[1];
        float4 o0, o1;
        o0.x = acc[0] * 0.125f + bv0.x;
        o0.y = acc[1] * 0.125f + bv0.y;
        o0.z = acc[2] * 0.125f + bv0.z;
        o0.w = acc[3] * 0.125f + bv0.w;
        o1.x = acc[4] * 0.125f + bv1.x;
        o1.y = acc[5] * 0.125f + bv1.y;
        o1.z = acc[6] * 0.125f + bv1.z;
        o1.w = acc[7] * 0.125f + bv1.w;
        if (dorelu) {
            o0.x = fmaxf(o0.x, 0.f); o0.y = fmaxf(o0.y, 0.f);
            o0.z = fmaxf(o0.z, 0.f); o0.w = fmaxf(o0.w, 0.f);
            o1.x = fmaxf(o1.x, 0.f); o1.y = fmaxf(o1.y, 0.f);
            o1.z = fmaxf(o1.z, 0.f); o1.w = fmaxf(o1.w, 0.f);
        }
        float4* op = (float4*)(xout + (size_t)gw * CH + 8 * lane);
        op[0] = o0;
        op[1] = o1;
    }
}

// ---------------------------------------------------------------------------
// Pool: batch sorted -> run-local accumulation, atomic flush per boundary.
__global__ void pool_kernel(const float* __restrict__ x, const int* __restrict__ batch,
                            float* __restrict__ pools, float* __restrict__ pcnt,
                            int N, int chunk) {
    int c  = threadIdx.x & 63;
    int nl = threadIdx.x >> 6;   // 0..3
    int n0 = blockIdx.x * chunk;
    int n1 = min(n0 + chunk, N);
    float acc = 0.f, cnt = 0.f;
    int curg = -1;
    for (int n = n0 + nl; n < n1; n += 4) {
        int g = batch[n];
        if (g != curg) {
            if (curg >= 0) {
                atomicAdd(pools + (size_t)curg * CH + c, acc);
                if (c == 0) atomicAdd(pcnt + curg, cnt);
            }
            curg = g; acc = 0.f; cnt = 0.f;
        }
        acc += x[(size_t)n * CH + c];
        cnt += 1.f;
    }
    if (curg >= 0) {
        atomicAdd(pools + (size_t)curg * CH + c, acc);
        if (c == 0) atomicAdd(pcnt + curg, cnt);
    }
}

__global__ void final_kernel(const float* __restrict__ pools, const float* __restrict__ pcnt,
                             const float* __restrict__ linW, const float* __restrict__ linb,
                             float* __restrict__ out) {
    int t = threadIdx.x;
    if (t >= NGR * 2) return;
    int g = t >> 1, k = t & 1;
    float inv = 1.f / fmaxf(pcnt[g], 1.f);
    float acc = 0.f;
#pragma unroll
    for (int c = 0; c < CH; c++)
        acc += pools[(size_t)g * CH + c] * inv * linW[c * 2 + k];
    out[g * 2 + k] = acc + linb[k];
}

// ---------------------------------------------------------------------------
extern "C" void kernel_launch(void* const* d_in, const int* in_sizes, int n_in,
                              void* d_out, int out_size, void* d_ws, size_t ws_size,
                              hipStream_t stream) {
    const float* x      = (const float*)d_in[0];
    const int*   ei     = (const int*)d_in[1];
    const int*   batch  = (const int*)d_in[3];
    const float* gamma  = (const float*)d_in[4];
    const float* beta   = (const float*)d_in[5];
    const float* W1     = (const float*)d_in[6];
    const float* a1s    = (const float*)d_in[7];
    const float* a1d    = (const float*)d_in[8];
    const float* b1     = (const float*)d_in[9];
    const float* W2     = (const float*)d_in[10];
    const float* a2s    = (const float*)d_in[11];
    const float* a2d    = (const float*)d_in[12];
    const float* b2     = (const float*)d_in[13];
    const float* W3     = (const float*)d_in[14];
    const float* a3s    = (const float*)d_in[15];
    const float* a3d    = (const float*)d_in[16];
    const float* b3     = (const float*)d_in[17];
    const float* linW   = (const float*)d_in[18];
    const float* linb   = (const float*)d_in[19];
    float* out = (float*)d_out;

    const int N  = in_sizes[0] / 16;
    const int E  = in_sizes[1] / 2;
    const int E2 = E + N;

    // Workspace layout (256B aligned slices)
    char* p = (char*)d_ws;
    size_t off = 0;
    auto alloc = [&](size_t bytes) {
        void* r = p + off;
        off += (bytes + 255) & ~(size_t)255;
        return r;
    };
    __hip_bfloat16* hbuf = (__hip_bfloat16*)alloc((size_t)N * HC * 2);
    float* xa        = (float*)alloc((size_t)N * CH * 4);
    float* xb        = (float*)alloc((size_t)N * CH * 4);
    float* asv       = (float*)alloc((size_t)N * HEADS * 4);
    float* adv       = (float*)alloc((size_t)N * HEADS * 4);
    float* alpha_csr = (float*)alloc((size_t)E2 * HEADS * 4);
    float* stats     = (float*)alloc(64 * 4);
    float* partials  = (float*)alloc((size_t)BNB * 32 * 4);
    float* pools     = (float*)alloc((size_t)NGR * CH * 4);
    float* pcnt      = (float*)alloc(NGR * 4);
    int*   rowptr    = (int*)alloc((size_t)(N + 1) * 4);
    int*   cursor    = (int*)alloc((size_t)N * 4);
    int*   counts    = (int*)alloc((size_t)N * 4);
    int*   src_csr   = (int*)alloc((size_t)E2 * 4);
    int*   dst_csr   = (int*)alloc((size_t)E2 * 4);
    (void)ws_size;

    const int TB = 256;
    int gE2 = (E2 + TB - 1) / TB;
    int gEH = (E2 * 8 + TB - 1) / TB;
    int gGm = (N + 31) / 32;
    int gWv = (N * 64 + TB - 1) / TB;      // one wave per node
    const int PCHUNK = 256;
    int gPool = (N + PCHUNK - 1) / PCHUNK;
    int bnChunk = (N + BNB - 1) / BNB;

    const ushort* hb = (const ushort*)hbuf;

    // zero-init accumulators
    hipMemsetAsync(counts, 0, (size_t)N * 4, stream);
    hipMemsetAsync(pools, 0, (size_t)NGR * CH * 4, stream);
    hipMemsetAsync(pcnt, 0, NGR * 4, stream);

    // BN statistics (two-stage deterministic reduction, no atomics)
    bn_stats_kernel<<<BNB, TB, 0, stream>>>(x, partials, N, bnChunk);
    bn_finalize_kernel<<<1, 64, 0, stream>>>(partials, stats, gamma, beta, N, BNB);

    // CSR over dst
    count_kernel<<<gE2, TB, 0, stream>>>(ei, E, E2, counts);
    scan_kernel<<<1, 1024, 0, stream>>>(counts, rowptr, cursor, N);
    scatter_kernel<<<gE2, TB, 0, stream>>>(ei, E, E2, cursor, src_csr, dst_csr);

    // ---- Layer 1 (BN fused into GEMM staging) ----
    gemm_kernel<16><<<gGm, TB, 0, stream>>>(x, W1, hbuf, N, stats + 32, stats + 48);
    asad_kernel<<<gWv, TB, 0, stream>>>(hb, a1s, a1d, asv, adv, N);
    alpha_kernel<<<gEH, TB, 0, stream>>>(src_csr, dst_csr, asv, adv, alpha_csr, E2);
    agg_kernel<<<gWv, TB, 0, stream>>>(rowptr, src_csr, alpha_csr, hb, b1, xa, N, 1);

    // ---- Layer 2 ----
    gemm_kernel<64><<<gGm, TB, 0, stream>>>(xa, W2, hbuf, N, nullptr, nullptr);
    asad_kernel<<<gWv, TB, 0, stream>>>(hb, a2s, a2d, asv, adv, N);
    alpha_kernel<<<gEH, TB, 0, stream>>>(src_csr, dst_csr, asv, adv, alpha_csr, E2);
    agg_kernel<<<gWv, TB, 0, stream>>>(rowptr, src_csr, alpha_csr, hb, b2, xb, N, 1);

    // ---- Layer 3 ----
    gemm_kernel<64><<<gGm, TB, 0, stream>>>(xb, W3, hbuf, N, nullptr, nullptr);
    asad_kernel<<<gWv, TB, 0, stream>>>(hb, a3s, a3d, asv, adv, N);
    alpha_kernel<<<gEH, TB, 0, stream>>>(src_csr, dst_csr, asv, adv, alpha_csr, E2);
    agg_kernel<<<gWv, TB, 0, stream>>>(rowptr, src_csr, alpha_csr, hb, b3, xa, N, 0);

    // ---- Pool + final linear ----
    pool_kernel<<<gPool, TB, 0, stream>>>(xa, batch, pools, pcnt, N, PCHUNK);
    final_kernel<<<1, 128, 0, stream>>>(pools, pcnt, linW, linb, out);
}